// Round 8
// baseline (111.961 us; speedup 1.0000x reference)
//
#include <hip/hip_runtime.h>
#include <hip/hip_bf16.h>
#include <math.h>

// Problem constants
#define B_ 4
#define T_ 4096
#define C_ 1024
#define H_ 128
#define SCALE 0.08838834764831845f  // 1/sqrt(128)

typedef __attribute__((ext_vector_type(8))) short bf16x8;
typedef __attribute__((ext_vector_type(4))) float f32x4;

__device__ __forceinline__ unsigned short f2bf(float f) {
    union { float f; unsigned u; } x; x.f = f;
    unsigned r = x.u + 0x7FFF + ((x.u >> 16) & 1);
    return (unsigned short)(r >> 16);
}
__device__ __forceinline__ float bf2f(unsigned short u) {
    union { unsigned u; float f; } x; x.u = ((unsigned)u) << 16;
    return x.f;
}
__device__ __forceinline__ unsigned cvt_pk_bf16(float a, float b) {
    unsigned r;
    asm("v_cvt_pk_bf16_f32 %0, %1, %2" : "=v"(r) : "v"(a), "v"(b));
    return r;
}
// convert 4x float4 -> 16 bf16 (explicit components; no pointer punning of locals)
__device__ __forceinline__ void cvt16(const float4& a, const float4& b,
                                      const float4& c, const float4& d,
                                      unsigned short* t) {
    t[0]=f2bf(a.x);  t[1]=f2bf(a.y);  t[2]=f2bf(a.z);  t[3]=f2bf(a.w);
    t[4]=f2bf(b.x);  t[5]=f2bf(b.y);  t[6]=f2bf(b.z);  t[7]=f2bf(b.w);
    t[8]=f2bf(c.x);  t[9]=f2bf(c.y);  t[10]=f2bf(c.z); t[11]=f2bf(c.w);
    t[12]=f2bf(d.x); t[13]=f2bf(d.y); t[14]=f2bf(d.z); t[15]=f2bf(d.w);
}

// async global->LDS, 16B per lane. gsrc: per-lane global addr; ldst: wave-uniform base.
#define GLOAD16(gsrc, ldst)                                                        \
    __builtin_amdgcn_global_load_lds(                                              \
        (const __attribute__((address_space(1))) unsigned int*)(gsrc),             \
        (__attribute__((address_space(3))) unsigned int*)(ldst), 16, 0, 0)

// ---------------------------------------------------------------------------
// Kernel 1: W [C,H] fp32  ->  Wt [t][h][c] bf16  (transposed, cast)
// ---------------------------------------------------------------------------
__global__ __launch_bounds__(256) void wtrans_kernel(
        const float* __restrict__ Wk, const float* __restrict__ Wq,
        const float* __restrict__ Wv, unsigned short* __restrict__ Wt) {
    int tid = blockIdx.x * 256 + threadIdx.x;
    int t = tid >> 17;
    int r = tid & 131071;
    int c = r >> 7;
    int h = r & 127;
    const float* W = (t == 0) ? Wk : (t == 1) ? Wq : Wv;
    Wt[t * 131072 + h * 1024 + c] = f2bf(W[r]);
}

// ---------------------------------------------------------------------------
// Kernel 2: QKV GEMM v2. Grid 512 (2 blocks/CU): block = 64 M-rows x 192 N.
// Double-buffered; Bs via global_load_lds (swizzled); As reg-convert with
// issue-early/write-late; counted vmcnt(10). v-part written directly to vT.
// ---------------------------------------------------------------------------
__global__ __launch_bounds__(256, 2) void qkv_gemm2(
        const float* __restrict__ x, const unsigned short* __restrict__ Wt,
        unsigned short* __restrict__ qkv, unsigned short* __restrict__ vT) {
    __shared__ unsigned short As[2][64][72];      // 18 KB, padded (2-way free)
    __shared__ unsigned short Bs[2][192][64];     // 48 KB, unpadded+swizzled

    const int nsw = blockIdx.x;
    const int sw = (nsw & 7) * 64 + (nsw >> 3);   // XCD-contiguous m-bands
    const int m0 = (sw >> 1) * 64;
    const int nh = sw & 1;

    const int tid = threadIdx.x;
    const int lane = tid & 63;
    const int w = tid >> 6;
    const int fr = lane & 15;
    const int fq = lane >> 4;

    // x staging: thread -> row tid>>2, 16-float column chunk
    const int xrow = tid >> 2, xco = (tid & 3) * 16;
    const float* xsrc = x + (long)(m0 + xrow) * C_ + xco;
    // Bs staging: wave chunk c = w*6+i covers rows 8c..8c+7 (1 KB per chunk)
    const int brl = lane >> 3;                     // row-in-chunk 0..7
    const int bcolb = (((lane & 7) ^ brl) << 4);   // inverse-swizzled col byte
    unsigned short* const bs_flat = &Bs[0][0][0];
    const unsigned short* wbase = Wt + (long)(nh * 192) * 1024;

    f32x4 acc[3][4];
#pragma unroll
    for (int i = 0; i < 3; i++)
#pragma unroll
        for (int rf = 0; rf < 4; rf++) acc[i][rf] = f32x4{0.f, 0.f, 0.f, 0.f};

    // prologue: x(0) loads first, then Bs(0) gloads (so x-wait keeps Bs in flight)
    float4 xr0, xr1, xr2, xr3;
    xr0 = ((const float4*)xsrc)[0]; xr1 = ((const float4*)xsrc)[1];
    xr2 = ((const float4*)xsrc)[2]; xr3 = ((const float4*)xsrc)[3];
#pragma unroll
    for (int i = 0; i < 6; i++)
        GLOAD16(wbase + (long)(48*w + 8*i + brl) * 1024 + (bcolb >> 1),
                bs_flat + (w*6 + i) * 512);
    {
        unsigned short tmp[16];
        cvt16(xr0, xr1, xr2, xr3, tmp);
        *(uint4*)&As[0][xrow][xco]     = ((uint4*)tmp)[0];
        *(uint4*)&As[0][xrow][xco + 8] = ((uint4*)tmp)[1];
    }

    int cur = 0;
    for (int k = 0; k < 16; ++k) {
        __syncthreads();   // X: all waves done MFMA(k-1); As[cur] writes visible
        const bool more = (k + 1) < 16;
        if (more) {
            const float* xs = xsrc + (k + 1) * 64;
            xr0 = ((const float4*)xs)[0]; xr1 = ((const float4*)xs)[1];
            xr2 = ((const float4*)xs)[2]; xr3 = ((const float4*)xs)[3];
            const int boff = (cur ^ 1) * 12288;    // shorts
#pragma unroll
            for (int i = 0; i < 6; i++)
                GLOAD16(wbase + (long)(48*w + 8*i + brl) * 1024 + (k + 1) * 64 + (bcolb >> 1),
                        bs_flat + boff + (w*6 + i) * 512);
            asm volatile("s_waitcnt vmcnt(10)" ::: "memory");  // Bs(k) landed
        } else {
            asm volatile("s_waitcnt vmcnt(0)" ::: "memory");
        }
        __syncthreads();   // Y: Bs[cur] visible from all waves

        const char* bsb = (const char*)bs_flat + cur * 24576;
        __builtin_amdgcn_s_setprio(1);
#pragma unroll
        for (int kk = 0; kk < 2; kk++) {
            bf16x8 a[4], bb[3];
#pragma unroll
            for (int rf = 0; rf < 4; rf++)
                a[rf] = *(const bf16x8*)&As[cur][rf*16 + fr][kk*32 + fq*8];
#pragma unroll
            for (int i = 0; i < 3; i++) {
                int row = (w*3 + i) * 16 + fr;
                bb[i] = *(const bf16x8*)(bsb + row*128 + ((((kk<<2) + fq) ^ (fr & 7)) << 4));
            }
#pragma unroll
            for (int i = 0; i < 3; i++)
#pragma unroll
                for (int rf = 0; rf < 4; rf++)
                    acc[i][rf] = __builtin_amdgcn_mfma_f32_16x16x32_bf16(
                        a[rf], bb[i], acc[i][rf], 0, 0, 0);
        }
        __builtin_amdgcn_s_setprio(0);

        if (more) {
            unsigned short tmp[16];
            cvt16(xr0, xr1, xr2, xr3, tmp);
            *(uint4*)&As[cur ^ 1][xrow][xco]     = ((uint4*)tmp)[0];
            *(uint4*)&As[cur ^ 1][xrow][xco + 8] = ((uint4*)tmp)[1];
        }
        cur ^= 1;
    }

    // epilogue: k/q -> qkv (bf16 scalar), v -> vT directly (8B stores)
#pragma unroll
    for (int i = 0; i < 3; i++) {
        int nfg = nh*12 + w*3 + i;
        int t = nfg >> 3;
        int col = (nfg & 7) * 16 + fr;
        if (t < 2) {
#pragma unroll
            for (int rf = 0; rf < 4; rf++)
#pragma unroll
                for (int r = 0; r < 4; r++) {
                    int row = m0 + rf*16 + fq*4 + r;
                    qkv[(long)t * 2097152 + (long)row * 128 + col] = f2bf(acc[i][rf][r]);
                }
        } else {
            const int bb_ = m0 >> 12;
            const int trow = m0 & 4095;
#pragma unroll
            for (int rf = 0; rf < 4; rf++) {
                uint2 uu;
                uu.x = cvt_pk_bf16(acc[i][rf][0], acc[i][rf][1]);
                uu.y = cvt_pk_bf16(acc[i][rf][2], acc[i][rf][3]);
                *(uint2*)(vT + ((long)(bb_*128 + col)) * 4096 + trow + rf*16 + fq*4) = uu;
            }
        }
    }
}

// ===========================================================================
// flash6: QB=128, KB=64, split-4, K+V double-buffered (64 KB), grid 512. (R6 proven)
// flash7: QB=128, KB=64, split-6, K dbuf + V single (48 KB), grid 768, 3 blk/CU.
// ===========================================================================

__global__ __launch_bounds__(512, 4) void flash6_kernel(
        const unsigned short* __restrict__ qkv,
        const unsigned short* __restrict__ vT,
        unsigned short* __restrict__ po0, unsigned short* __restrict__ po1,
        unsigned short* __restrict__ po2, unsigned short* __restrict__ po3,
        float* __restrict__ pm, float* __restrict__ pl) {
    __shared__ unsigned short k_lds[2][64][128];
    __shared__ unsigned short v_lds[2][128][64];

    const int n = blockIdx.x;
    const int half = n >> 8;
    const int m = n & 255;
    const int b = (m & 7) >> 1;
    const int r = ((m >> 3) << 1) | (m & 1);
    const int jj = r & 31;
    const int pq = r >> 5;
    const int qt = half ? (31 - jj) : jj;
    const int p = half * 2 + pq;
    const int q0 = qt * 128;
    const int ntt = (qt + 1) * 2;
    const int t0 = (p * ntt) >> 2;
    const int t1 = ((p + 1) * ntt) >> 2;

    const int tid = threadIdx.x;
    const int w = tid >> 6;
    const int lane = tid & 63;
    const int fr = lane & 15;
    const int fq = lane >> 4;

    const unsigned short* kbase = qkv + (long)b * T_ * H_;
    const unsigned short* vbase = vT + (long)b * H_ * T_;

    const int kcolb0 = ((lane & 15) << 4) ^ ((((lane >> 4)) & 7) << 4);
    const int kcolb1 = ((lane & 15) << 4) ^ (((4 + (lane >> 4)) & 7) << 4);
    const int krl = lane >> 4;
    const int vrl = lane >> 3;
    const int vcolb = ((lane & 7) << 4) ^ (vrl << 4);
    unsigned short* const klds_flat = &k_lds[0][0][0];
    unsigned short* const vlds_flat = &v_lds[0][0][0];
    const int scol = ((fq ^ (fr & 7)) << 4);

    bf16x8 qf[4];
    {
        const unsigned short* qptr = qkv + 2097152 + ((long)b*T_ + q0 + w*16 + fr) * H_;
#pragma unroll
        for (int ks = 0; ks < 4; ks++)
            qf[ks] = *(const bf16x8*)(qptr + ks*32 + fq*8);
    }

    f32x4 acc[8];
#pragma unroll
    for (int i = 0; i < 8; i++) acc[i] = f32x4{0.f, 0.f, 0.f, 0.f};
    float m_r = -INFINITY, l_r = 0.f;
    const int qrow = q0 + w*16 + fr;

    int cur = 0;
    if (t0 < t1) {
        const int kv0 = t0 * 64;
#pragma unroll
        for (int i = 0; i < 2; i++) {
            int kcolb = i ? kcolb1 : kcolb0;
            GLOAD16(kbase + (long)(kv0 + 8*w + 4*i + krl) * 128 + (kcolb >> 1),
                    klds_flat + w*1024 + i*512);
            GLOAD16(vbase + (long)(16*w + 8*i + vrl) * 4096 + kv0 + (vcolb >> 1),
                    vlds_flat + w*1024 + i*512);
        }
    }

    for (int t = t0; t < t1; ++t) {
        const int kv0 = t * 64;
        __syncthreads();
        if (t + 1 < t1) {
            const int kv0n = kv0 + 64;
            const int boff = (cur ^ 1) * 8192;
#pragma unroll
            for (int i = 0; i < 2; i++) {
                int kcolb = i ? kcolb1 : kcolb0;
                GLOAD16(kbase + (long)(kv0n + 8*w + 4*i + krl) * 128 + (kcolb >> 1),
                        klds_flat + boff + w*1024 + i*512);
                GLOAD16(vbase + (long)(16*w + 8*i + vrl) * 4096 + kv0n + (vcolb >> 1),
                        vlds_flat + boff + w*1024 + i*512);
            }
            asm volatile("s_waitcnt vmcnt(4)" ::: "memory");
        } else {
            asm volatile("s_waitcnt vmcnt(0)" ::: "memory");
        }
        __syncthreads();

        const char* kl = (const char*)k_lds + cur*16384 + fr*256;
        const char* vl = (const char*)v_lds + cur*16384 + fr*128;

        f32x4 s[4];
#pragma unroll
        for (int sf = 0; sf < 4; sf++) s[sf] = f32x4{0.f,0.f,0.f,0.f};
        __builtin_amdgcn_s_setprio(1);
#pragma unroll
        for (int sf = 0; sf < 4; sf++)
#pragma unroll
            for (int ks = 0; ks < 4; ks++) {
                bf16x8 kf = *(const bf16x8*)(kl + sf*4096 + (scol ^ (ks << 6)));
                s[sf] = __builtin_amdgcn_mfma_f32_16x16x32_bf16(kf, qf[ks], s[sf], 0, 0, 0);
            }
        __builtin_amdgcn_s_setprio(0);

        float mx = -INFINITY;
        if (kv0 + 63 > q0 + 16*w) {
#pragma unroll
            for (int sf = 0; sf < 4; sf++)
#pragma unroll
                for (int rr = 0; rr < 4; rr++) {
                    int kv = kv0 + sf*16 + fq*4 + rr;
                    float sv = s[sf][rr] * SCALE;
                    sv = (kv > qrow) ? -INFINITY : sv;
                    s[sf][rr] = sv;
                    mx = fmaxf(mx, sv);
                }
        } else {
#pragma unroll
            for (int sf = 0; sf < 4; sf++)
#pragma unroll
                for (int rr = 0; rr < 4; rr++) {
                    float sv = s[sf][rr] * SCALE;
                    s[sf][rr] = sv;
                    mx = fmaxf(mx, sv);
                }
        }
        mx = fmaxf(mx, __shfl_xor(mx, 16, 64));
        mx = fmaxf(mx, __shfl_xor(mx, 32, 64));

        const bool skip = __all((m_r > -1e37f) & (mx - m_r <= 8.f));
        float msub;
        if (skip) {
            msub = m_r;
        } else {
            float mn = fmaxf(m_r, mx);
            msub = (mn == -INFINITY) ? 0.f : mn;
            float alpha = __expf(m_r - msub);
            m_r = mn;
#pragma unroll
            for (int hf = 0; hf < 8; hf++)
#pragma unroll
                for (int rr = 0; rr < 4; rr++) acc[hf][rr] *= alpha;
            l_r *= alpha;
        }

        float pv[4][4];
        float sum = 0.f;
#pragma unroll
        for (int sf = 0; sf < 4; sf++)
#pragma unroll
            for (int rr = 0; rr < 4; rr++) {
                float e = __expf(s[sf][rr] - msub);
                pv[sf][rr] = e;
                sum += e;
            }
        sum += __shfl_xor(sum, 16, 64);
        sum += __shfl_xor(sum, 32, 64);
        l_r += sum;

        unsigned pw[8];
#pragma unroll
        for (int sf = 0; sf < 4; sf++) {
            pw[2*sf]   = cvt_pk_bf16(pv[sf][0], pv[sf][1]);
            pw[2*sf+1] = cvt_pk_bf16(pv[sf][2], pv[sf][3]);
        }
        unsigned pbu[2][4];
        pbu[0][0]=0;pbu[0][1]=0;pbu[0][2]=0;pbu[0][3]=0;
        pbu[1][0]=0;pbu[1][1]=0;pbu[1][2]=0;pbu[1][3]=0;
        const int L1 = fr + 16 * ((fq & 1) * 2);
        const int L2 = L1 + 16;
        const int sel = (fq >> 1) & 1;
#pragma unroll
        for (int sf = 0; sf < 4; sf++) {
            unsigned w0 = (unsigned)__shfl((int)pw[2*sf],   L1, 64);
            unsigned w1 = (unsigned)__shfl((int)pw[2*sf+1], L1, 64);
            unsigned w2 = (unsigned)__shfl((int)pw[2*sf],   L2, 64);
            unsigned w3 = (unsigned)__shfl((int)pw[2*sf+1], L2, 64);
            if ((sf & 1) == sel) {
                int k2 = sf >> 1;
                pbu[k2][0] = w0; pbu[k2][1] = w1; pbu[k2][2] = w2; pbu[k2][3] = w3;
            }
        }
        union { unsigned u[4]; bf16x8 v; } pb0c, pb1c;
#pragma unroll
        for (int i = 0; i < 4; i++) { pb0c.u[i] = pbu[0][i]; pb1c.u[i] = pbu[1][i]; }
        bf16x8 pb0 = pb0c.v, pb1 = pb1c.v;

        __builtin_amdgcn_s_setprio(1);
#pragma unroll
        for (int hf = 0; hf < 8; hf++) {
            bf16x8 vf0 = *(const bf16x8*)(vl + hf*2048 + scol);
            bf16x8 vf1 = *(const bf16x8*)(vl + hf*2048 + (scol ^ 64));
            acc[hf] = __builtin_amdgcn_mfma_f32_16x16x32_bf16(vf0, pb0, acc[hf], 0, 0, 0);
            acc[hf] = __builtin_amdgcn_mfma_f32_16x16x32_bf16(vf1, pb1, acc[hf], 0, 0, 0);
        }
        __builtin_amdgcn_s_setprio(0);
        cur ^= 1;
    }

    unsigned short* po = (p == 0) ? po0 : (p == 1) ? po1 : (p == 2) ? po2 : po3;
    float linv = (l_r > 0.f) ? (1.0f / l_r) : 0.f;
    const long obase = ((long)b * T_ + qrow) * H_;
#pragma unroll
    for (int hf = 0; hf < 8; hf++) {
        uint2 uu;
        uu.x = cvt_pk_bf16(acc[hf][0] * linv, acc[hf][1] * linv);
        uu.y = cvt_pk_bf16(acc[hf][2] * linv, acc[hf][3] * linv);
        *(uint2*)(po + obase + hf*16 + fq*4) = uu;
    }
    if (fq == 0) {
        pm[p * 16384 + b * T_ + qrow] = m_r;
        pl[p * 16384 + b * T_ + qrow] = l_r;
    }
}

// flash7: split-6, V single-buffered, 48 KB LDS, 3 blocks/CU (grid 768)
__global__ __launch_bounds__(512, 6) void flash7_kernel(
        const unsigned short* __restrict__ qkv,
        const unsigned short* __restrict__ vT,
        unsigned short* __restrict__ po,
        float* __restrict__ pm, float* __restrict__ pl) {
    __shared__ unsigned short k_lds[2][64][128];   // 32 KB dbuf
    __shared__ unsigned short v_lds[128][64];      // 16 KB single

    const int n = blockIdx.x;                     // 0..767
    const int b = (n & 7) >> 1;
    const int r = ((n >> 3) << 1) | (n & 1);      // 0..191
    const int p = r % 6;
    const int qt = 31 - (r / 6);                  // longest first
    const int q0 = qt * 128;
    const int ntt = (qt + 1) * 2;
    const int t0 = (p * ntt) / 6;
    const int t1 = ((p + 1) * ntt) / 6;

    const int tid = threadIdx.x;
    const int w = tid >> 6;
    const int lane = tid & 63;
    const int fr = lane & 15;
    const int fq = lane >> 4;

    const unsigned short* kbase = qkv + (long)b * T_ * H_;
    const unsigned short* vbase = vT + (long)b * H_ * T_;

    const int kcolb0 = ((lane & 15) << 4) ^ ((((lane >> 4)) & 7) << 4);
    const int kcolb1 = ((lane & 15) << 4) ^ (((4 + (lane >> 4)) & 7) << 4);
    const int krl = lane >> 4;
    const int vrl = lane >> 3;
    const int vcolb = ((lane & 7) << 4) ^ (vrl << 4);
    unsigned short* const klds_flat = &k_lds[0][0][0];
    unsigned short* const vlds_flat = &v_lds[0][0];
    const int scol = ((fq ^ (fr & 7)) << 4);

    bf16x8 qf[4];
    {
        const unsigned short* qptr = qkv + 2097152 + ((long)b*T_ + q0 + w*16 + fr) * H_;
#pragma unroll
        for (int ks = 0; ks < 4; ks++)
            qf[ks] = *(const bf16x8*)(qptr + ks*32 + fq*8);
    }

    f32x4 acc[8];
#pragma unroll
    for (int i = 0; i < 8; i++) acc[i] = f32x4{0.f, 0.f, 0.f, 0.f};
    float m_r = -INFINITY, l_r = 0.f;
    const int qrow = q0 + w*16 + fr;

    int cur = 0;
    if (t0 < t1) {
        const int kv0 = t0 * 64;
#pragma unroll
        for (int i = 0; i < 2; i++) {
            int kcolb = i ? kcolb1 : kcolb0;
            GLOAD16(kbase + (long)(kv0 + 8*w + 4*i + krl) * 128 + (kcolb >> 1),
                    klds_flat + w*1024 + i*512);
        }
    }

    for (int t = t0; t < t1; ++t) {
        const int kv0 = t * 64;
        __syncthreads();   // A: PV(t-1)+QK^T(t-1) reads done; vbuf & k[cur^1] free
        // issue V(t), then K(t+1); queue = [K(t)2, V(t)2, K(t+1)2]
#pragma unroll
        for (int i = 0; i < 2; i++)
            GLOAD16(vbase + (long)(16*w + 8*i + vrl) * 4096 + kv0 + (vcolb >> 1),
                    vlds_flat + w*1024 + i*512);
        if (t + 1 < t1) {
            const int kv0n = kv0 + 64;
            const int boff = (cur ^ 1) * 8192;
#pragma unroll
            for (int i = 0; i < 2; i++) {
                int kcolb = i ? kcolb1 : kcolb0;
                GLOAD16(kbase + (long)(kv0n + 8*w + 4*i + krl) * 128 + (kcolb >> 1),
                        klds_flat + boff + w*1024 + i*512);
            }
            asm volatile("s_waitcnt vmcnt(4)" ::: "memory");   // K(t) landed
        } else {
            asm volatile("s_waitcnt vmcnt(2)" ::: "memory");   // K(t) landed
        }
        __syncthreads();   // B: K(t) visible

        const char* kl = (const char*)k_lds + cur*16384 + fr*256;
        const char* vl = (const char*)v_lds + fr*128;

        f32x4 s[4];
#pragma unroll
        for (int sf = 0; sf < 4; sf++) s[sf] = f32x4{0.f,0.f,0.f,0.f};
        __builtin_amdgcn_s_setprio(1);
#pragma unroll
        for (int sf = 0; sf < 4; sf++)
#pragma unroll
            for (int ks = 0; ks < 4; ks++) {
                bf16x8 kf = *(const bf16x8*)(kl + sf*4096 + (scol ^ (ks << 6)));
                s[sf] = __builtin_amdgcn_mfma_f32_16x16x32_bf16(kf, qf[ks], s[sf], 0, 0, 0);
            }
        __builtin_amdgcn_s_setprio(0);

        float mx = -INFINITY;
        if (kv0 + 63 > q0 + 16*w) {
#pragma unroll
            for (int sf = 0; sf < 4; sf++)
#pragma unroll
                for (int rr = 0; rr < 4; rr++) {
                    int kv = kv0 + sf*16 + fq*4 + rr;
                    float sv = s[sf][rr] * SCALE;
                    sv = (kv > qrow) ? -INFINITY : sv;
                    s[sf][rr] = sv;
                    mx = fmaxf(mx, sv);
                }
        } else {
#pragma unroll
            for (int sf = 0; sf < 4; sf++)
#pragma unroll
                for (int rr = 0; rr < 4; rr++) {
                    float sv = s[sf][rr] * SCALE;
                    s[sf][rr] = sv;
                    mx = fmaxf(mx, sv);
                }
        }
        mx = fmaxf(mx, __shfl_xor(mx, 16, 64));
        mx = fmaxf(mx, __shfl_xor(mx, 32, 64));

        const bool skip = __all((m_r > -1e37f) & (mx - m_r <= 8.f));
        float msub;
        if (skip) {
            msub = m_r;
        } else {
            float mn = fmaxf(m_r, mx);
            msub = (mn == -INFINITY) ? 0.f : mn;
            float alpha = __expf(m_r - msub);
            m_r = mn;
#pragma unroll
            for (int hf = 0; hf < 8; hf++)
#pragma unroll
                for (int rr = 0; rr < 4; rr++) acc[hf][rr] *= alpha;
            l_r *= alpha;
        }

        float pv[4][4];
        float sum = 0.f;
#pragma unroll
        for (int sf = 0; sf < 4; sf++)
#pragma unroll
            for (int rr = 0; rr < 4; rr++) {
                float e = __expf(s[sf][rr] - msub);
                pv[sf][rr] = e;
                sum += e;
            }
        sum += __shfl_xor(sum, 16, 64);
        sum += __shfl_xor(sum, 32, 64);
        l_r += sum;

        unsigned pw[8];
#pragma unroll
        for (int sf = 0; sf < 4; sf++) {
            pw[2*sf]   = cvt_pk_bf16(pv[sf][0], pv[sf][1]);
            pw[2*sf+1] = cvt_pk_bf16(pv[sf][2], pv[sf][3]);
        }
        unsigned pbu[2][4];
        pbu[0][0]=0;pbu[0][1]=0;pbu[0][2]=0;pbu[0][3]=0;
        pbu[1][0]=0;pbu[1][1]=0;pbu[1][2]=0;pbu[1][3]=0;
        const int L1 = fr + 16 * ((fq & 1) * 2);
        const int L2 = L1 + 16;
        const int sel = (fq >> 1) & 1;
#pragma unroll
        for (int sf = 0; sf < 4; sf++) {
            unsigned w0 = (unsigned)__shfl((int)pw[2*sf],   L1, 64);
            unsigned w1 = (unsigned)__shfl((int)pw[2*sf+1], L1, 64);
            unsigned w2 = (unsigned)__shfl((int)pw[2*sf],   L2, 64);
            unsigned w3 = (unsigned)__shfl((int)pw[2*sf+1], L2, 64);
            if ((sf & 1) == sel) {
                int k2 = sf >> 1;
                pbu[k2][0] = w0; pbu[k2][1] = w1; pbu[k2][2] = w2; pbu[k2][3] = w3;
            }
        }
        union { unsigned u[4]; bf16x8 v; } pb0c, pb1c;
#pragma unroll
        for (int i = 0; i < 4; i++) { pb0c.u[i] = pbu[0][i]; pb1c.u[i] = pbu[1][i]; }
        bf16x8 pb0 = pb0c.v, pb1 = pb1c.v;

        if (t + 1 < t1) asm volatile("s_waitcnt vmcnt(2)" ::: "memory");  // V(t) landed
        else            asm volatile("s_waitcnt vmcnt(0)" ::: "memory");
        __syncthreads();   // C: V(t) visible

        __builtin_amdgcn_s_setprio(1);
#pragma unroll
        for (int hf = 0; hf < 8; hf++) {
            bf16x8 vf0 = *(const bf16x8*)(vl + hf*2048 + scol);
            bf16x8 vf1 = *(const bf16x8*)(vl + hf*2048 + (scol ^ 64));
            acc[hf] = __builtin_amdgcn_mfma_f32_16x16x32_bf16(vf0, pb0, acc[hf], 0, 0, 0);
            acc[hf] = __builtin_amdgcn_mfma_f32_16x16x32_bf16(vf1, pb1, acc[hf], 0, 0, 0);
        }
        __builtin_amdgcn_s_setprio(0);
        cur ^= 1;
    }

    float linv = (l_r > 0.f) ? (1.0f / l_r) : 0.f;
    const long obase = (long)p * 2097152 + ((long)b * T_ + qrow) * H_;
#pragma unroll
    for (int hf = 0; hf < 8; hf++) {
        uint2 uu;
        uu.x = cvt_pk_bf16(acc[hf][0] * linv, acc[hf][1] * linv);
        uu.y = cvt_pk_bf16(acc[hf][2] * linv, acc[hf][3] * linv);
        *(uint2*)(po + obase + hf*16 + fq*4) = uu;
    }
    if (fq == 0) {
        pm[p * 16384 + b * T_ + qrow] = m_r;
        pl[p * 16384 + b * T_ + qrow] = l_r;
    }
}

// ---------------------------------------------------------------------------
// Combine kernels
// ---------------------------------------------------------------------------
__global__ __launch_bounds__(256) void combine4_kernel(
        const unsigned short* __restrict__ po0,
        const unsigned short* __restrict__ po1,
        const unsigned short* __restrict__ po2,
        const unsigned short* __restrict__ po3,
        const float* __restrict__ pm, const float* __restrict__ pl,
        float* __restrict__ out) {
    int idx = blockIdx.x * 256 + threadIdx.x;
    int row = idx >> 4;
    int seg = idx & 15;
    float mv[4], lv[4];
#pragma unroll
    for (int i = 0; i < 4; i++) { mv[i] = pm[i*16384 + row]; lv[i] = pl[i*16384 + row]; }
    float m = fmaxf(fmaxf(mv[0], mv[1]), fmaxf(mv[2], mv[3]));
    float wv[4]; float tot = 0.f;
#pragma unroll
    for (int i = 0; i < 4; i++) {
        wv[i] = (lv[i] > 0.f) ? __expf(mv[i] - m) * lv[i] : 0.f;
        tot += wv[i];
    }
    float inv = 1.0f / tot;
    long off = (long)row * H_ + seg * 8;
    unsigned short ua[8], ub[8], uc[8], ud[8];
    *(uint4*)ua = *(const uint4*)(po0 + off);
    *(uint4*)ub = *(const uint4*)(po1 + off);
    *(uint4*)uc = *(const uint4*)(po2 + off);
    *(uint4*)ud = *(const uint4*)(po3 + off);
    float* o = out + off;
#pragma unroll
    for (int j2 = 0; j2 < 8; j2++)
        o[j2] = inv * (wv[0] * bf2f(ua[j2]) + wv[1] * bf2f(ub[j2]) +
                       wv[2] * bf2f(uc[j2]) + wv[3] * bf2f(ud[j2]));
}

__global__ __launch_bounds__(256) void combine6_kernel(
        const unsigned short* __restrict__ po,
        const float* __restrict__ pm, const float* __restrict__ pl,
        float* __restrict__ out) {
    int idx = blockIdx.x * 256 + threadIdx.x;
    int row = idx >> 4;
    int seg = idx & 15;
    float mv[6], lv[6];
#pragma unroll
    for (int i = 0; i < 6; i++) { mv[i] = pm[i*16384 + row]; lv[i] = pl[i*16384 + row]; }
    float m = mv[0];
#pragma unroll
    for (int i = 1; i < 6; i++) m = fmaxf(m, mv[i]);
    float wv[6]; float tot = 0.f;
#pragma unroll
    for (int i = 0; i < 6; i++) {
        wv[i] = (lv[i] > 0.f) ? __expf(mv[i] - m) * lv[i] : 0.f;
        tot += wv[i];
    }
    float inv = 1.0f / tot;
    long off = (long)row * H_ + seg * 8;
    float* o = out + off;
    float res[8];
#pragma unroll
    for (int j2 = 0; j2 < 8; j2++) res[j2] = 0.f;
#pragma unroll
    for (int i = 0; i < 6; i++) {
        unsigned short ua[8];
        *(uint4*)ua = *(const uint4*)(po + (long)i * 2097152 + off);
#pragma unroll
        for (int j2 = 0; j2 < 8; j2++) res[j2] += wv[i] * bf2f(ua[j2]);
    }
#pragma unroll
    for (int j2 = 0; j2 < 8; j2++) o[j2] = inv * res[j2];
}

// ---------------------------------------------------------------------------
extern "C" void kernel_launch(void* const* d_in, const int* in_sizes, int n_in,
                              void* d_out, int out_size, void* d_ws, size_t ws_size,
                              hipStream_t stream) {
    (void)in_sizes; (void)n_in; (void)out_size;
    const float* x  = (const float*)d_in[0];
    const float* Wk = (const float*)d_in[1];
    const float* Wq = (const float*)d_in[2];
    const float* Wv = (const float*)d_in[3];
    float* out = (float*)d_out;

    unsigned short* Wt  = (unsigned short*)d_ws;       // 393216 shorts
    unsigned short* qkv = Wt + 393216;                 // k | q | (v slot unused)
    unsigned short* vT  = qkv + 6291456;               // 2097152

    wtrans_kernel<<<1536, 256, 0, stream>>>(Wk, Wq, Wv, Wt);
    qkv_gemm2<<<512, 256, 0, stream>>>(x, Wt, qkv, vT);

    // flash7 (split-6, 3 blk/CU) needs 42.73 MB of ws; fall back to flash6.
    const size_t need7 = ((size_t)393216 + 10u * 2097152u) * 2u;   // 42,729,472
    if (ws_size >= need7) {
        unsigned short* po = vT + 2097152;             // 6 x 2097152 contiguous
        float* pm = (float*)d_ws;                      // 6 x 16384 (alias Wt)
        float* pl = pm + 98304;
        flash7_kernel<<<768, 512, 0, stream>>>(qkv, vT, po, pm, pl);
        combine6_kernel<<<1024, 256, 0, stream>>>(po, pm, pl, out);
    } else {
        unsigned short* po0 = vT + 2097152;
        unsigned short* po1 = po0 + 2097152;
        unsigned short* po3 = po1 + 2097152;
        unsigned short* po2 = qkv + 4194304;           // aliases unused v slot
        float* pm = (float*)d_ws;                      // 4 x 16384 (alias Wt)
        float* pl = pm + 65536;
        flash6_kernel<<<512, 512, 0, stream>>>(qkv, vT, po0, po1, po2, po3, pm, pl);
        combine4_kernel<<<1024, 256, 0, stream>>>(po0, po1, po2, po3, pm, pl, out);
    }
}

// Round 9
// 83.301 us; speedup vs baseline: 1.3440x; 1.3440x over previous
//
#include <hip/hip_runtime.h>
#include <hip/hip_bf16.h>
#include <math.h>

// Problem constants
#define B_ 4
#define T_ 4096
#define C_ 1024
#define H_ 128
#define SCALE 0.08838834764831845f  // 1/sqrt(128)

typedef __attribute__((ext_vector_type(8))) short bf16x8;
typedef __attribute__((ext_vector_type(4))) float f32x4;

__device__ __forceinline__ unsigned short f2bf(float f) {
    union { float f; unsigned u; } x; x.f = f;
    unsigned r = x.u + 0x7FFF + ((x.u >> 16) & 1);
    return (unsigned short)(r >> 16);
}
__device__ __forceinline__ float bf2f(unsigned short u) {
    union { unsigned u; float f; } x; x.u = ((unsigned)u) << 16;
    return x.f;
}
__device__ __forceinline__ unsigned cvt_pk_bf16(float a, float b) {
    unsigned r;
    asm("v_cvt_pk_bf16_f32 %0, %1, %2" : "=v"(r) : "v"(a), "v"(b));
    return r;
}
// convert 4x float4 -> 16 bf16 (explicit components; no pointer punning of locals)
__device__ __forceinline__ void cvt16(const float4& a, const float4& b,
                                      const float4& c, const float4& d,
                                      unsigned short* t) {
    t[0]=f2bf(a.x);  t[1]=f2bf(a.y);  t[2]=f2bf(a.z);  t[3]=f2bf(a.w);
    t[4]=f2bf(b.x);  t[5]=f2bf(b.y);  t[6]=f2bf(b.z);  t[7]=f2bf(b.w);
    t[8]=f2bf(c.x);  t[9]=f2bf(c.y);  t[10]=f2bf(c.z); t[11]=f2bf(c.w);
    t[12]=f2bf(d.x); t[13]=f2bf(d.y); t[14]=f2bf(d.z); t[15]=f2bf(d.w);
}

// async global->LDS, 16B per lane. gsrc: per-lane global addr; ldst: wave-uniform base.
#define GLOAD16(gsrc, ldst)                                                        \
    __builtin_amdgcn_global_load_lds(                                              \
        (const __attribute__((address_space(1))) unsigned int*)(gsrc),             \
        (__attribute__((address_space(3))) unsigned int*)(ldst), 16, 0, 0)

// ---------------------------------------------------------------------------
// Kernel 1: W [C,H] fp32  ->  Wt [t][h][c] bf16  (transposed, cast)
// ---------------------------------------------------------------------------
__global__ __launch_bounds__(256) void wtrans_kernel(
        const float* __restrict__ Wk, const float* __restrict__ Wq,
        const float* __restrict__ Wv, unsigned short* __restrict__ Wt) {
    int tid = blockIdx.x * 256 + threadIdx.x;
    int t = tid >> 17;
    int r = tid & 131071;
    int c = r >> 7;
    int h = r & 127;
    const float* W = (t == 0) ? Wk : (t == 1) ? Wq : Wv;
    Wt[t * 131072 + h * 1024 + c] = f2bf(W[r]);
}

// ---------------------------------------------------------------------------
// Kernel 2: QKV GEMM v2. Grid 512 (2 blocks/CU): block = 64 M-rows x 192 N.
// Double-buffered; Bs via global_load_lds (swizzled); As reg-convert with
// issue-early/write-late; counted vmcnt(10). v-part written directly to vT.
// ---------------------------------------------------------------------------
__global__ __launch_bounds__(256, 2) void qkv_gemm2(
        const float* __restrict__ x, const unsigned short* __restrict__ Wt,
        unsigned short* __restrict__ qkv, unsigned short* __restrict__ vT) {
    __shared__ unsigned short As[2][64][72];      // 18 KB, padded (2-way free)
    __shared__ unsigned short Bs[2][192][64];     // 48 KB, unpadded+swizzled

    const int nsw = blockIdx.x;
    const int sw = (nsw & 7) * 64 + (nsw >> 3);   // XCD-contiguous m-bands
    const int m0 = (sw >> 1) * 64;
    const int nh = sw & 1;

    const int tid = threadIdx.x;
    const int lane = tid & 63;
    const int w = tid >> 6;
    const int fr = lane & 15;
    const int fq = lane >> 4;

    // x staging: thread -> row tid>>2, 16-float column chunk
    const int xrow = tid >> 2, xco = (tid & 3) * 16;
    const float* xsrc = x + (long)(m0 + xrow) * C_ + xco;
    // Bs staging: wave chunk c = w*6+i covers rows 8c..8c+7 (1 KB per chunk)
    const int brl = lane >> 3;                     // row-in-chunk 0..7
    const int bcolb = (((lane & 7) ^ brl) << 4);   // inverse-swizzled col byte
    unsigned short* const bs_flat = &Bs[0][0][0];
    const unsigned short* wbase = Wt + (long)(nh * 192) * 1024;

    f32x4 acc[3][4];
#pragma unroll
    for (int i = 0; i < 3; i++)
#pragma unroll
        for (int rf = 0; rf < 4; rf++) acc[i][rf] = f32x4{0.f, 0.f, 0.f, 0.f};

    // prologue: x(0) loads first, then Bs(0) gloads (so x-wait keeps Bs in flight)
    float4 xr0, xr1, xr2, xr3;
    xr0 = ((const float4*)xsrc)[0]; xr1 = ((const float4*)xsrc)[1];
    xr2 = ((const float4*)xsrc)[2]; xr3 = ((const float4*)xsrc)[3];
#pragma unroll
    for (int i = 0; i < 6; i++)
        GLOAD16(wbase + (long)(48*w + 8*i + brl) * 1024 + (bcolb >> 1),
                bs_flat + (w*6 + i) * 512);
    {
        unsigned short tmp[16];
        cvt16(xr0, xr1, xr2, xr3, tmp);
        *(uint4*)&As[0][xrow][xco]     = ((uint4*)tmp)[0];
        *(uint4*)&As[0][xrow][xco + 8] = ((uint4*)tmp)[1];
    }

    int cur = 0;
    for (int k = 0; k < 16; ++k) {
        __syncthreads();   // X: all waves done MFMA(k-1); As[cur] writes visible
        const bool more = (k + 1) < 16;
        if (more) {
            const float* xs = xsrc + (k + 1) * 64;
            xr0 = ((const float4*)xs)[0]; xr1 = ((const float4*)xs)[1];
            xr2 = ((const float4*)xs)[2]; xr3 = ((const float4*)xs)[3];
            const int boff = (cur ^ 1) * 12288;    // shorts
#pragma unroll
            for (int i = 0; i < 6; i++)
                GLOAD16(wbase + (long)(48*w + 8*i + brl) * 1024 + (k + 1) * 64 + (bcolb >> 1),
                        bs_flat + boff + (w*6 + i) * 512);
            asm volatile("s_waitcnt vmcnt(10)" ::: "memory");  // Bs(k) landed
        } else {
            asm volatile("s_waitcnt vmcnt(0)" ::: "memory");
        }
        __syncthreads();   // Y: Bs[cur] visible from all waves

        const char* bsb = (const char*)bs_flat + cur * 24576;
        __builtin_amdgcn_s_setprio(1);
#pragma unroll
        for (int kk = 0; kk < 2; kk++) {
            bf16x8 a[4], bb[3];
#pragma unroll
            for (int rf = 0; rf < 4; rf++)
                a[rf] = *(const bf16x8*)&As[cur][rf*16 + fr][kk*32 + fq*8];
#pragma unroll
            for (int i = 0; i < 3; i++) {
                int row = (w*3 + i) * 16 + fr;
                bb[i] = *(const bf16x8*)(bsb + row*128 + ((((kk<<2) + fq) ^ (fr & 7)) << 4));
            }
#pragma unroll
            for (int i = 0; i < 3; i++)
#pragma unroll
                for (int rf = 0; rf < 4; rf++)
                    acc[i][rf] = __builtin_amdgcn_mfma_f32_16x16x32_bf16(
                        a[rf], bb[i], acc[i][rf], 0, 0, 0);
        }
        __builtin_amdgcn_s_setprio(0);

        if (more) {
            unsigned short tmp[16];
            cvt16(xr0, xr1, xr2, xr3, tmp);
            *(uint4*)&As[cur ^ 1][xrow][xco]     = ((uint4*)tmp)[0];
            *(uint4*)&As[cur ^ 1][xrow][xco + 8] = ((uint4*)tmp)[1];
        }
        cur ^= 1;
    }

    // epilogue: k/q -> qkv (bf16 scalar), v -> vT directly (8B stores)
#pragma unroll
    for (int i = 0; i < 3; i++) {
        int nfg = nh*12 + w*3 + i;
        int t = nfg >> 3;
        int col = (nfg & 7) * 16 + fr;
        if (t < 2) {
#pragma unroll
            for (int rf = 0; rf < 4; rf++)
#pragma unroll
                for (int r = 0; r < 4; r++) {
                    int row = m0 + rf*16 + fq*4 + r;
                    qkv[(long)t * 2097152 + (long)row * 128 + col] = f2bf(acc[i][rf][r]);
                }
        } else {
            const int bb_ = m0 >> 12;
            const int trow = m0 & 4095;
#pragma unroll
            for (int rf = 0; rf < 4; rf++) {
                uint2 uu;
                uu.x = cvt_pk_bf16(acc[i][rf][0], acc[i][rf][1]);
                uu.y = cvt_pk_bf16(acc[i][rf][2], acc[i][rf][3]);
                *(uint2*)(vT + ((long)(bb_*128 + col)) * 4096 + trow + rf*16 + fq*4) = uu;
            }
        }
    }
}

// ---------------------------------------------------------------------------
// Kernel 3 (R6-proven): flash6. QB=128, KB=64, split-4, K+V double-buffered
// (64 KB), grid 512 = exactly 2 blocks/CU. Swapped-QK^T in-register softmax,
// defer-max, global_load_lds staging.
// ---------------------------------------------------------------------------
__global__ __launch_bounds__(512, 4) void flash6_kernel(
        const unsigned short* __restrict__ qkv,
        const unsigned short* __restrict__ vT,
        unsigned short* __restrict__ po0, unsigned short* __restrict__ po1,
        unsigned short* __restrict__ po2, unsigned short* __restrict__ po3,
        float* __restrict__ pm, float* __restrict__ pl) {
    __shared__ unsigned short k_lds[2][64][128];
    __shared__ unsigned short v_lds[2][128][64];

    const int n = blockIdx.x;
    const int half = n >> 8;
    const int m = n & 255;
    const int b = (m & 7) >> 1;
    const int r = ((m >> 3) << 1) | (m & 1);
    const int jj = r & 31;
    const int pq = r >> 5;
    const int qt = half ? (31 - jj) : jj;
    const int p = half * 2 + pq;
    const int q0 = qt * 128;
    const int ntt = (qt + 1) * 2;
    const int t0 = (p * ntt) >> 2;
    const int t1 = ((p + 1) * ntt) >> 2;

    const int tid = threadIdx.x;
    const int w = tid >> 6;
    const int lane = tid & 63;
    const int fr = lane & 15;
    const int fq = lane >> 4;

    const unsigned short* kbase = qkv + (long)b * T_ * H_;
    const unsigned short* vbase = vT + (long)b * H_ * T_;

    const int kcolb0 = ((lane & 15) << 4) ^ ((((lane >> 4)) & 7) << 4);
    const int kcolb1 = ((lane & 15) << 4) ^ (((4 + (lane >> 4)) & 7) << 4);
    const int krl = lane >> 4;
    const int vrl = lane >> 3;
    const int vcolb = ((lane & 7) << 4) ^ (vrl << 4);
    unsigned short* const klds_flat = &k_lds[0][0][0];
    unsigned short* const vlds_flat = &v_lds[0][0][0];
    const int scol = ((fq ^ (fr & 7)) << 4);

    bf16x8 qf[4];
    {
        const unsigned short* qptr = qkv + 2097152 + ((long)b*T_ + q0 + w*16 + fr) * H_;
#pragma unroll
        for (int ks = 0; ks < 4; ks++)
            qf[ks] = *(const bf16x8*)(qptr + ks*32 + fq*8);
    }

    f32x4 acc[8];
#pragma unroll
    for (int i = 0; i < 8; i++) acc[i] = f32x4{0.f, 0.f, 0.f, 0.f};
    float m_r = -INFINITY, l_r = 0.f;
    const int qrow = q0 + w*16 + fr;

    int cur = 0;
    if (t0 < t1) {
        const int kv0 = t0 * 64;
#pragma unroll
        for (int i = 0; i < 2; i++) {
            int kcolb = i ? kcolb1 : kcolb0;
            GLOAD16(kbase + (long)(kv0 + 8*w + 4*i + krl) * 128 + (kcolb >> 1),
                    klds_flat + w*1024 + i*512);
            GLOAD16(vbase + (long)(16*w + 8*i + vrl) * 4096 + kv0 + (vcolb >> 1),
                    vlds_flat + w*1024 + i*512);
        }
    }

    for (int t = t0; t < t1; ++t) {
        const int kv0 = t * 64;
        __syncthreads();
        if (t + 1 < t1) {
            const int kv0n = kv0 + 64;
            const int boff = (cur ^ 1) * 8192;
#pragma unroll
            for (int i = 0; i < 2; i++) {
                int kcolb = i ? kcolb1 : kcolb0;
                GLOAD16(kbase + (long)(kv0n + 8*w + 4*i + krl) * 128 + (kcolb >> 1),
                        klds_flat + boff + w*1024 + i*512);
                GLOAD16(vbase + (long)(16*w + 8*i + vrl) * 4096 + kv0n + (vcolb >> 1),
                        vlds_flat + boff + w*1024 + i*512);
            }
            asm volatile("s_waitcnt vmcnt(4)" ::: "memory");
        } else {
            asm volatile("s_waitcnt vmcnt(0)" ::: "memory");
        }
        __syncthreads();

        const char* kl = (const char*)k_lds + cur*16384 + fr*256;
        const char* vl = (const char*)v_lds + cur*16384 + fr*128;

        f32x4 s[4];
#pragma unroll
        for (int sf = 0; sf < 4; sf++) s[sf] = f32x4{0.f,0.f,0.f,0.f};
        __builtin_amdgcn_s_setprio(1);
#pragma unroll
        for (int sf = 0; sf < 4; sf++)
#pragma unroll
            for (int ks = 0; ks < 4; ks++) {
                bf16x8 kf = *(const bf16x8*)(kl + sf*4096 + (scol ^ (ks << 6)));
                s[sf] = __builtin_amdgcn_mfma_f32_16x16x32_bf16(kf, qf[ks], s[sf], 0, 0, 0);
            }
        __builtin_amdgcn_s_setprio(0);

        float mx = -INFINITY;
        if (kv0 + 63 > q0 + 16*w) {
#pragma unroll
            for (int sf = 0; sf < 4; sf++)
#pragma unroll
                for (int rr = 0; rr < 4; rr++) {
                    int kv = kv0 + sf*16 + fq*4 + rr;
                    float sv = s[sf][rr] * SCALE;
                    sv = (kv > qrow) ? -INFINITY : sv;
                    s[sf][rr] = sv;
                    mx = fmaxf(mx, sv);
                }
        } else {
#pragma unroll
            for (int sf = 0; sf < 4; sf++)
#pragma unroll
                for (int rr = 0; rr < 4; rr++) {
                    float sv = s[sf][rr] * SCALE;
                    s[sf][rr] = sv;
                    mx = fmaxf(mx, sv);
                }
        }
        mx = fmaxf(mx, __shfl_xor(mx, 16, 64));
        mx = fmaxf(mx, __shfl_xor(mx, 32, 64));

        const bool skip = __all((m_r > -1e37f) & (mx - m_r <= 8.f));
        float msub;
        if (skip) {
            msub = m_r;
        } else {
            float mn = fmaxf(m_r, mx);
            msub = (mn == -INFINITY) ? 0.f : mn;
            float alpha = __expf(m_r - msub);
            m_r = mn;
#pragma unroll
            for (int hf = 0; hf < 8; hf++)
#pragma unroll
                for (int rr = 0; rr < 4; rr++) acc[hf][rr] *= alpha;
            l_r *= alpha;
        }

        float pv[4][4];
        float sum = 0.f;
#pragma unroll
        for (int sf = 0; sf < 4; sf++)
#pragma unroll
            for (int rr = 0; rr < 4; rr++) {
                float e = __expf(s[sf][rr] - msub);
                pv[sf][rr] = e;
                sum += e;
            }
        sum += __shfl_xor(sum, 16, 64);
        sum += __shfl_xor(sum, 32, 64);
        l_r += sum;

        unsigned pw[8];
#pragma unroll
        for (int sf = 0; sf < 4; sf++) {
            pw[2*sf]   = cvt_pk_bf16(pv[sf][0], pv[sf][1]);
            pw[2*sf+1] = cvt_pk_bf16(pv[sf][2], pv[sf][3]);
        }
        unsigned pbu[2][4];
        pbu[0][0]=0;pbu[0][1]=0;pbu[0][2]=0;pbu[0][3]=0;
        pbu[1][0]=0;pbu[1][1]=0;pbu[1][2]=0;pbu[1][3]=0;
        const int L1 = fr + 16 * ((fq & 1) * 2);
        const int L2 = L1 + 16;
        const int sel = (fq >> 1) & 1;
#pragma unroll
        for (int sf = 0; sf < 4; sf++) {
            unsigned w0 = (unsigned)__shfl((int)pw[2*sf],   L1, 64);
            unsigned w1 = (unsigned)__shfl((int)pw[2*sf+1], L1, 64);
            unsigned w2 = (unsigned)__shfl((int)pw[2*sf],   L2, 64);
            unsigned w3 = (unsigned)__shfl((int)pw[2*sf+1], L2, 64);
            if ((sf & 1) == sel) {
                int k2 = sf >> 1;
                pbu[k2][0] = w0; pbu[k2][1] = w1; pbu[k2][2] = w2; pbu[k2][3] = w3;
            }
        }
        union { unsigned u[4]; bf16x8 v; } pb0c, pb1c;
#pragma unroll
        for (int i = 0; i < 4; i++) { pb0c.u[i] = pbu[0][i]; pb1c.u[i] = pbu[1][i]; }
        bf16x8 pb0 = pb0c.v, pb1 = pb1c.v;

        __builtin_amdgcn_s_setprio(1);
#pragma unroll
        for (int hf = 0; hf < 8; hf++) {
            bf16x8 vf0 = *(const bf16x8*)(vl + hf*2048 + scol);
            bf16x8 vf1 = *(const bf16x8*)(vl + hf*2048 + (scol ^ 64));
            acc[hf] = __builtin_amdgcn_mfma_f32_16x16x32_bf16(vf0, pb0, acc[hf], 0, 0, 0);
            acc[hf] = __builtin_amdgcn_mfma_f32_16x16x32_bf16(vf1, pb1, acc[hf], 0, 0, 0);
        }
        __builtin_amdgcn_s_setprio(0);
        cur ^= 1;
    }

    unsigned short* po = (p == 0) ? po0 : (p == 1) ? po1 : (p == 2) ? po2 : po3;
    float linv = (l_r > 0.f) ? (1.0f / l_r) : 0.f;
    const long obase = ((long)b * T_ + qrow) * H_;
#pragma unroll
    for (int hf = 0; hf < 8; hf++) {
        uint2 uu;
        uu.x = cvt_pk_bf16(acc[hf][0] * linv, acc[hf][1] * linv);
        uu.y = cvt_pk_bf16(acc[hf][2] * linv, acc[hf][3] * linv);
        *(uint2*)(po + obase + hf*16 + fq*4) = uu;
    }
    if (fq == 0) {
        pm[p * 16384 + b * T_ + qrow] = m_r;
        pl[p * 16384 + b * T_ + qrow] = l_r;
    }
}

// ---------------------------------------------------------------------------
// Kernel 4: combine the four KV-parts
// ---------------------------------------------------------------------------
__global__ __launch_bounds__(256) void combine4_kernel(
        const unsigned short* __restrict__ po0,
        const unsigned short* __restrict__ po1,
        const unsigned short* __restrict__ po2,
        const unsigned short* __restrict__ po3,
        const float* __restrict__ pm, const float* __restrict__ pl,
        float* __restrict__ out) {
    int idx = blockIdx.x * 256 + threadIdx.x;
    int row = idx >> 4;
    int seg = idx & 15;
    float mv[4], lv[4];
#pragma unroll
    for (int i = 0; i < 4; i++) { mv[i] = pm[i*16384 + row]; lv[i] = pl[i*16384 + row]; }
    float m = fmaxf(fmaxf(mv[0], mv[1]), fmaxf(mv[2], mv[3]));
    float wv[4]; float tot = 0.f;
#pragma unroll
    for (int i = 0; i < 4; i++) {
        wv[i] = (lv[i] > 0.f) ? __expf(mv[i] - m) * lv[i] : 0.f;
        tot += wv[i];
    }
    float inv = 1.0f / tot;
    long off = (long)row * H_ + seg * 8;
    unsigned short ua[8], ub[8], uc[8], ud[8];
    *(uint4*)ua = *(const uint4*)(po0 + off);
    *(uint4*)ub = *(const uint4*)(po1 + off);
    *(uint4*)uc = *(const uint4*)(po2 + off);
    *(uint4*)ud = *(const uint4*)(po3 + off);
    float* o = out + off;
#pragma unroll
    for (int j2 = 0; j2 < 8; j2++)
        o[j2] = inv * (wv[0] * bf2f(ua[j2]) + wv[1] * bf2f(ub[j2]) +
                       wv[2] * bf2f(uc[j2]) + wv[3] * bf2f(ud[j2]));
}

// ---------------------------------------------------------------------------
extern "C" void kernel_launch(void* const* d_in, const int* in_sizes, int n_in,
                              void* d_out, int out_size, void* d_ws, size_t ws_size,
                              hipStream_t stream) {
    (void)in_sizes; (void)n_in; (void)out_size; (void)ws_size;
    const float* x  = (const float*)d_in[0];
    const float* Wk = (const float*)d_in[1];
    const float* Wq = (const float*)d_in[2];
    const float* Wv = (const float*)d_in[3];
    float* out = (float*)d_out;

    // ws layout (shorts). pm/pl alias Wt (dead after gemm2); po2 aliases the
    // unused qkv v-slot. Total ~30 MB.
    unsigned short* Wt  = (unsigned short*)d_ws;       // 393216 shorts
    unsigned short* qkv = Wt + 393216;                 // k | q | (v slot unused)
    unsigned short* vT  = qkv + 6291456;               // 2097152
    unsigned short* po0 = vT + 2097152;
    unsigned short* po1 = po0 + 2097152;
    unsigned short* po3 = po1 + 2097152;
    unsigned short* po2 = qkv + 4194304;               // aliases unused v slot
    float* pm = (float*)d_ws;                          // 4 x 16384 (alias Wt)
    float* pl = pm + 65536;

    wtrans_kernel<<<1536, 256, 0, stream>>>(Wk, Wq, Wv, Wt);
    qkv_gemm2<<<512, 256, 0, stream>>>(x, Wt, qkv, vT);
    flash6_kernel<<<512, 512, 0, stream>>>(qkv, vT, po0, po1, po2, po3, pm, pl);
    combine4_kernel<<<1024, 256, 0, stream>>>(po0, po1, po2, po3, pm, pl, out);
}

// Round 10
// 80.331 us; speedup vs baseline: 1.3937x; 1.0370x over previous
//
#include <hip/hip_runtime.h>
#include <hip/hip_bf16.h>
#include <math.h>

// Problem constants
#define B_ 4
#define T_ 4096
#define C_ 1024
#define H_ 128
#define SCALE 0.08838834764831845f  // 1/sqrt(128)

typedef __attribute__((ext_vector_type(8))) short bf16x8;
typedef __attribute__((ext_vector_type(4))) float f32x4;

__device__ __forceinline__ unsigned short f2bf(float f) {
    union { float f; unsigned u; } x; x.f = f;
    unsigned r = x.u + 0x7FFF + ((x.u >> 16) & 1);
    return (unsigned short)(r >> 16);
}
__device__ __forceinline__ float bf2f(unsigned short u) {
    union { unsigned u; float f; } x; x.u = ((unsigned)u) << 16;
    return x.f;
}
__device__ __forceinline__ unsigned cvt_pk_bf16(float a, float b) {
    unsigned r;
    asm("v_cvt_pk_bf16_f32 %0, %1, %2" : "=v"(r) : "v"(a), "v"(b));
    return r;
}
// 16 floats -> 8 packed bf16 words via v_cvt_pk_bf16_f32 (lo = first arg)
__device__ __forceinline__ void cvt16(const float4& a, const float4& b,
                                      const float4& c, const float4& d,
                                      unsigned* t) {
    t[0]=cvt_pk_bf16(a.x,a.y); t[1]=cvt_pk_bf16(a.z,a.w);
    t[2]=cvt_pk_bf16(b.x,b.y); t[3]=cvt_pk_bf16(b.z,b.w);
    t[4]=cvt_pk_bf16(c.x,c.y); t[5]=cvt_pk_bf16(c.z,c.w);
    t[6]=cvt_pk_bf16(d.x,d.y); t[7]=cvt_pk_bf16(d.z,d.w);
}

// async global->LDS, 16B per lane. gsrc: per-lane global addr; ldst: wave-uniform base.
#define GLOAD16(gsrc, ldst)                                                        \
    __builtin_amdgcn_global_load_lds(                                              \
        (const __attribute__((address_space(1))) unsigned int*)(gsrc),             \
        (__attribute__((address_space(3))) unsigned int*)(ldst), 16, 0, 0)

// ---------------------------------------------------------------------------
// Kernel 1: W [C,H] fp32  ->  Wt [t][h][c] bf16  (transposed, cast)
// ---------------------------------------------------------------------------
__global__ __launch_bounds__(256) void wtrans_kernel(
        const float* __restrict__ Wk, const float* __restrict__ Wq,
        const float* __restrict__ Wv, unsigned short* __restrict__ Wt) {
    int tid = blockIdx.x * 256 + threadIdx.x;
    int t = tid >> 17;
    int r = tid & 131071;
    int c = r >> 7;
    int h = r & 127;
    const float* W = (t == 0) ? Wk : (t == 1) ? Wq : Wv;
    Wt[t * 131072 + h * 1024 + c] = f2bf(W[r]);
}

// ---------------------------------------------------------------------------
// Kernel 2: QKV GEMM v2. Grid 512 (2 blocks/CU): block = 64 M-rows x 192 N.
// Double-buffered; Bs via global_load_lds (swizzled); As reg-convert (cvt_pk)
// with issue-early/write-late; counted vmcnt(10). v-part written to vT.
// ---------------------------------------------------------------------------
__global__ __launch_bounds__(256, 2) void qkv_gemm2(
        const float* __restrict__ x, const unsigned short* __restrict__ Wt,
        unsigned short* __restrict__ qkv, unsigned short* __restrict__ vT) {
    __shared__ unsigned short As[2][64][72];      // 18 KB, padded (2-way free)
    __shared__ unsigned short Bs[2][192][64];     // 48 KB, unpadded+swizzled

    const int nsw = blockIdx.x;
    const int sw = (nsw & 7) * 64 + (nsw >> 3);   // XCD-contiguous m-bands
    const int m0 = (sw >> 1) * 64;
    const int nh = sw & 1;

    const int tid = threadIdx.x;
    const int lane = tid & 63;
    const int w = tid >> 6;
    const int fr = lane & 15;
    const int fq = lane >> 4;

    const int xrow = tid >> 2, xco = (tid & 3) * 16;
    const float* xsrc = x + (long)(m0 + xrow) * C_ + xco;
    const int brl = lane >> 3;
    const int bcolb = (((lane & 7) ^ brl) << 4);
    unsigned short* const bs_flat = &Bs[0][0][0];
    const unsigned short* wbase = Wt + (long)(nh * 192) * 1024;

    f32x4 acc[3][4];
#pragma unroll
    for (int i = 0; i < 3; i++)
#pragma unroll
        for (int rf = 0; rf < 4; rf++) acc[i][rf] = f32x4{0.f, 0.f, 0.f, 0.f};

    float4 xr0, xr1, xr2, xr3;
    xr0 = ((const float4*)xsrc)[0]; xr1 = ((const float4*)xsrc)[1];
    xr2 = ((const float4*)xsrc)[2]; xr3 = ((const float4*)xsrc)[3];
#pragma unroll
    for (int i = 0; i < 6; i++)
        GLOAD16(wbase + (long)(48*w + 8*i + brl) * 1024 + (bcolb >> 1),
                bs_flat + (w*6 + i) * 512);
    {
        unsigned tw[8];
        cvt16(xr0, xr1, xr2, xr3, tw);
        *(uint4*)&As[0][xrow][xco]     = uint4{tw[0], tw[1], tw[2], tw[3]};
        *(uint4*)&As[0][xrow][xco + 8] = uint4{tw[4], tw[5], tw[6], tw[7]};
    }

    int cur = 0;
    for (int k = 0; k < 16; ++k) {
        __syncthreads();   // X: all waves done MFMA(k-1); As[cur] writes visible
        const bool more = (k + 1) < 16;
        if (more) {
            const float* xs = xsrc + (k + 1) * 64;
            xr0 = ((const float4*)xs)[0]; xr1 = ((const float4*)xs)[1];
            xr2 = ((const float4*)xs)[2]; xr3 = ((const float4*)xs)[3];
            const int boff = (cur ^ 1) * 12288;    // shorts
#pragma unroll
            for (int i = 0; i < 6; i++)
                GLOAD16(wbase + (long)(48*w + 8*i + brl) * 1024 + (k + 1) * 64 + (bcolb >> 1),
                        bs_flat + boff + (w*6 + i) * 512);
            asm volatile("s_waitcnt vmcnt(10)" ::: "memory");  // Bs(k) landed
        } else {
            asm volatile("s_waitcnt vmcnt(0)" ::: "memory");
        }
        __syncthreads();   // Y: Bs[cur] visible from all waves

        const char* bsb = (const char*)bs_flat + cur * 24576;
        __builtin_amdgcn_s_setprio(1);
#pragma unroll
        for (int kk = 0; kk < 2; kk++) {
            bf16x8 a[4], bb[3];
#pragma unroll
            for (int rf = 0; rf < 4; rf++)
                a[rf] = *(const bf16x8*)&As[cur][rf*16 + fr][kk*32 + fq*8];
#pragma unroll
            for (int i = 0; i < 3; i++) {
                int row = (w*3 + i) * 16 + fr;
                bb[i] = *(const bf16x8*)(bsb + row*128 + ((((kk<<2) + fq) ^ (fr & 7)) << 4));
            }
#pragma unroll
            for (int i = 0; i < 3; i++)
#pragma unroll
                for (int rf = 0; rf < 4; rf++)
                    acc[i][rf] = __builtin_amdgcn_mfma_f32_16x16x32_bf16(
                        a[rf], bb[i], acc[i][rf], 0, 0, 0);
        }
        __builtin_amdgcn_s_setprio(0);

        if (more) {
            unsigned tw[8];
            cvt16(xr0, xr1, xr2, xr3, tw);
            *(uint4*)&As[cur ^ 1][xrow][xco]     = uint4{tw[0], tw[1], tw[2], tw[3]};
            *(uint4*)&As[cur ^ 1][xrow][xco + 8] = uint4{tw[4], tw[5], tw[6], tw[7]};
        }
        cur ^= 1;
    }

    // epilogue: k/q -> qkv (bf16 scalar), v -> vT directly (8B stores)
#pragma unroll
    for (int i = 0; i < 3; i++) {
        int nfg = nh*12 + w*3 + i;
        int t = nfg >> 3;
        int col = (nfg & 7) * 16 + fr;
        if (t < 2) {
#pragma unroll
            for (int rf = 0; rf < 4; rf++)
#pragma unroll
                for (int r = 0; r < 4; r++) {
                    int row = m0 + rf*16 + fq*4 + r;
                    qkv[(long)t * 2097152 + (long)row * 128 + col] = f2bf(acc[i][rf][r]);
                }
        } else {
            const int bb_ = m0 >> 12;
            const int trow = m0 & 4095;
#pragma unroll
            for (int rf = 0; rf < 4; rf++) {
                uint2 uu;
                uu.x = cvt_pk_bf16(acc[i][rf][0], acc[i][rf][1]);
                uu.y = cvt_pk_bf16(acc[i][rf][2], acc[i][rf][3]);
                *(uint2*)(vT + ((long)(bb_*128 + col)) * 4096 + trow + rf*16 + fq*4) = uu;
            }
        }
    }
}

// ---------------------------------------------------------------------------
// Kernel 3: flash8 = flash6 with a 1-barrier pipelined tile loop.
// Per wave, iter t: {vmcnt(0): own t-loads landed (issued one compute phase
// ago); barrier: all waves' t-loads visible AND everyone done reading buf^1;
// issue(t+1)->buf^1 (latency hides under compute(t)); compute(t)}.
// QB=128, KB=64, split-4, grid 512 = exactly 2 blocks/CU.
// ---------------------------------------------------------------------------
__global__ __launch_bounds__(512, 4) void flash8_kernel(
        const unsigned short* __restrict__ qkv,
        const unsigned short* __restrict__ vT,
        unsigned short* __restrict__ po0, unsigned short* __restrict__ po1,
        unsigned short* __restrict__ po2, unsigned short* __restrict__ po3,
        float* __restrict__ pm, float* __restrict__ pl) {
    __shared__ unsigned short k_lds[2][64][128];
    __shared__ unsigned short v_lds[2][128][64];

    const int n = blockIdx.x;
    const int half = n >> 8;
    const int m = n & 255;
    const int b = (m & 7) >> 1;
    const int r = ((m >> 3) << 1) | (m & 1);
    const int jj = r & 31;
    const int pq = r >> 5;
    const int qt = half ? (31 - jj) : jj;
    const int p = half * 2 + pq;
    const int q0 = qt * 128;
    const int ntt = (qt + 1) * 2;
    const int t0 = (p * ntt) >> 2;
    const int t1 = ((p + 1) * ntt) >> 2;

    const int tid = threadIdx.x;
    const int w = tid >> 6;
    const int lane = tid & 63;
    const int fr = lane & 15;
    const int fq = lane >> 4;

    const unsigned short* kbase = qkv + (long)b * T_ * H_;
    const unsigned short* vbase = vT + (long)b * H_ * T_;

    const int kcolb0 = ((lane & 15) << 4) ^ ((((lane >> 4)) & 7) << 4);
    const int kcolb1 = ((lane & 15) << 4) ^ (((4 + (lane >> 4)) & 7) << 4);
    const int krl = lane >> 4;
    const int vrl = lane >> 3;
    const int vcolb = ((lane & 7) << 4) ^ (vrl << 4);
    unsigned short* const klds_flat = &k_lds[0][0][0];
    unsigned short* const vlds_flat = &v_lds[0][0][0];
    const int scol = ((fq ^ (fr & 7)) << 4);

    bf16x8 qf[4];
    {
        const unsigned short* qptr = qkv + 2097152 + ((long)b*T_ + q0 + w*16 + fr) * H_;
#pragma unroll
        for (int ks = 0; ks < 4; ks++)
            qf[ks] = *(const bf16x8*)(qptr + ks*32 + fq*8);
    }

    f32x4 acc[8];
#pragma unroll
    for (int i = 0; i < 8; i++) acc[i] = f32x4{0.f, 0.f, 0.f, 0.f};
    float m_r = -INFINITY, l_r = 0.f;
    const int qrow = q0 + w*16 + fr;

    int cur = 0;
    if (t0 < t1) {
        const int kv0 = t0 * 64;
#pragma unroll
        for (int i = 0; i < 2; i++) {
            int kcolb = i ? kcolb1 : kcolb0;
            GLOAD16(kbase + (long)(kv0 + 8*w + 4*i + krl) * 128 + (kcolb >> 1),
                    klds_flat + w*1024 + i*512);
            GLOAD16(vbase + (long)(16*w + 8*i + vrl) * 4096 + kv0 + (vcolb >> 1),
                    vlds_flat + w*1024 + i*512);
        }
    }

    for (int t = t0; t < t1; ++t) {
        const int kv0 = t * 64;
        asm volatile("s_waitcnt vmcnt(0)" ::: "memory");  // own tile-t loads landed
        __syncthreads();  // all t-loads visible; all waves done reading buf^1
        if (t + 1 < t1) {
            const int kv0n = kv0 + 64;
            const int boff = (cur ^ 1) * 8192;
#pragma unroll
            for (int i = 0; i < 2; i++) {
                int kcolb = i ? kcolb1 : kcolb0;
                GLOAD16(kbase + (long)(kv0n + 8*w + 4*i + krl) * 128 + (kcolb >> 1),
                        klds_flat + boff + w*1024 + i*512);
                GLOAD16(vbase + (long)(16*w + 8*i + vrl) * 4096 + kv0n + (vcolb >> 1),
                        vlds_flat + boff + w*1024 + i*512);
            }
        }

        const char* kl = (const char*)k_lds + cur*16384 + fr*256;
        const char* vl = (const char*)v_lds + cur*16384 + fr*128;

        f32x4 s[4];
#pragma unroll
        for (int sf = 0; sf < 4; sf++) s[sf] = f32x4{0.f,0.f,0.f,0.f};
        __builtin_amdgcn_s_setprio(1);
#pragma unroll
        for (int sf = 0; sf < 4; sf++)
#pragma unroll
            for (int ks = 0; ks < 4; ks++) {
                bf16x8 kf = *(const bf16x8*)(kl + sf*4096 + (scol ^ (ks << 6)));
                s[sf] = __builtin_amdgcn_mfma_f32_16x16x32_bf16(kf, qf[ks], s[sf], 0, 0, 0);
            }
        __builtin_amdgcn_s_setprio(0);

        float mx = -INFINITY;
        if (kv0 + 63 > q0 + 16*w) {
#pragma unroll
            for (int sf = 0; sf < 4; sf++)
#pragma unroll
                for (int rr = 0; rr < 4; rr++) {
                    int kv = kv0 + sf*16 + fq*4 + rr;
                    float sv = s[sf][rr] * SCALE;
                    sv = (kv > qrow) ? -INFINITY : sv;
                    s[sf][rr] = sv;
                    mx = fmaxf(mx, sv);
                }
        } else {
#pragma unroll
            for (int sf = 0; sf < 4; sf++)
#pragma unroll
                for (int rr = 0; rr < 4; rr++) {
                    float sv = s[sf][rr] * SCALE;
                    s[sf][rr] = sv;
                    mx = fmaxf(mx, sv);
                }
        }
        mx = fmaxf(mx, __shfl_xor(mx, 16, 64));
        mx = fmaxf(mx, __shfl_xor(mx, 32, 64));

        const bool skip = __all((m_r > -1e37f) & (mx - m_r <= 8.f));
        float msub;
        if (skip) {
            msub = m_r;
        } else {
            float mn = fmaxf(m_r, mx);
            msub = (mn == -INFINITY) ? 0.f : mn;
            float alpha = __expf(m_r - msub);
            m_r = mn;
#pragma unroll
            for (int hf = 0; hf < 8; hf++)
#pragma unroll
                for (int rr = 0; rr < 4; rr++) acc[hf][rr] *= alpha;
            l_r *= alpha;
        }

        float pv[4][4];
        float sum = 0.f;
#pragma unroll
        for (int sf = 0; sf < 4; sf++)
#pragma unroll
            for (int rr = 0; rr < 4; rr++) {
                float e = __expf(s[sf][rr] - msub);
                pv[sf][rr] = e;
                sum += e;
            }
        sum += __shfl_xor(sum, 16, 64);
        sum += __shfl_xor(sum, 32, 64);
        l_r += sum;

        unsigned pw[8];
#pragma unroll
        for (int sf = 0; sf < 4; sf++) {
            pw[2*sf]   = cvt_pk_bf16(pv[sf][0], pv[sf][1]);
            pw[2*sf+1] = cvt_pk_bf16(pv[sf][2], pv[sf][3]);
        }
        unsigned pbu[2][4];
        pbu[0][0]=0;pbu[0][1]=0;pbu[0][2]=0;pbu[0][3]=0;
        pbu[1][0]=0;pbu[1][1]=0;pbu[1][2]=0;pbu[1][3]=0;
        const int L1 = fr + 16 * ((fq & 1) * 2);
        const int L2 = L1 + 16;
        const int sel = (fq >> 1) & 1;
#pragma unroll
        for (int sf = 0; sf < 4; sf++) {
            unsigned w0 = (unsigned)__shfl((int)pw[2*sf],   L1, 64);
            unsigned w1 = (unsigned)__shfl((int)pw[2*sf+1], L1, 64);
            unsigned w2 = (unsigned)__shfl((int)pw[2*sf],   L2, 64);
            unsigned w3 = (unsigned)__shfl((int)pw[2*sf+1], L2, 64);
            if ((sf & 1) == sel) {
                int k2 = sf >> 1;
                pbu[k2][0] = w0; pbu[k2][1] = w1; pbu[k2][2] = w2; pbu[k2][3] = w3;
            }
        }
        union { unsigned u[4]; bf16x8 v; } pb0c, pb1c;
#pragma unroll
        for (int i = 0; i < 4; i++) { pb0c.u[i] = pbu[0][i]; pb1c.u[i] = pbu[1][i]; }
        bf16x8 pb0 = pb0c.v, pb1 = pb1c.v;

        __builtin_amdgcn_s_setprio(1);
#pragma unroll
        for (int hf = 0; hf < 8; hf++) {
            bf16x8 vf0 = *(const bf16x8*)(vl + hf*2048 + scol);
            bf16x8 vf1 = *(const bf16x8*)(vl + hf*2048 + (scol ^ 64));
            acc[hf] = __builtin_amdgcn_mfma_f32_16x16x32_bf16(vf0, pb0, acc[hf], 0, 0, 0);
            acc[hf] = __builtin_amdgcn_mfma_f32_16x16x32_bf16(vf1, pb1, acc[hf], 0, 0, 0);
        }
        __builtin_amdgcn_s_setprio(0);
        cur ^= 1;
    }

    unsigned short* po = (p == 0) ? po0 : (p == 1) ? po1 : (p == 2) ? po2 : po3;
    float linv = (l_r > 0.f) ? (1.0f / l_r) : 0.f;
    const long obase = ((long)b * T_ + qrow) * H_;
#pragma unroll
    for (int hf = 0; hf < 8; hf++) {
        uint2 uu;
        uu.x = cvt_pk_bf16(acc[hf][0] * linv, acc[hf][1] * linv);
        uu.y = cvt_pk_bf16(acc[hf][2] * linv, acc[hf][3] * linv);
        *(uint2*)(po + obase + hf*16 + fq*4) = uu;
    }
    if (fq == 0) {
        pm[p * 16384 + b * T_ + qrow] = m_r;
        pl[p * 16384 + b * T_ + qrow] = l_r;
    }
}

// ---------------------------------------------------------------------------
// Kernel 4: combine the four KV-parts
// ---------------------------------------------------------------------------
__global__ __launch_bounds__(256) void combine4_kernel(
        const unsigned short* __restrict__ po0,
        const unsigned short* __restrict__ po1,
        const unsigned short* __restrict__ po2,
        const unsigned short* __restrict__ po3,
        const float* __restrict__ pm, const float* __restrict__ pl,
        float* __restrict__ out) {
    int idx = blockIdx.x * 256 + threadIdx.x;
    int row = idx >> 4;
    int seg = idx & 15;
    float mv[4], lv[4];
#pragma unroll
    for (int i = 0; i < 4; i++) { mv[i] = pm[i*16384 + row]; lv[i] = pl[i*16384 + row]; }
    float m = fmaxf(fmaxf(mv[0], mv[1]), fmaxf(mv[2], mv[3]));
    float wv[4]; float tot = 0.f;
#pragma unroll
    for (int i = 0; i < 4; i++) {
        wv[i] = (lv[i] > 0.f) ? __expf(mv[i] - m) * lv[i] : 0.f;
        tot += wv[i];
    }
    float inv = 1.0f / tot;
    long off = (long)row * H_ + seg * 8;
    unsigned short ua[8], ub[8], uc[8], ud[8];
    *(uint4*)ua = *(const uint4*)(po0 + off);
    *(uint4*)ub = *(const uint4*)(po1 + off);
    *(uint4*)uc = *(const uint4*)(po2 + off);
    *(uint4*)ud = *(const uint4*)(po3 + off);
    float* o = out + off;
#pragma unroll
    for (int j2 = 0; j2 < 8; j2++)
        o[j2] = inv * (wv[0] * bf2f(ua[j2]) + wv[1] * bf2f(ub[j2]) +
                       wv[2] * bf2f(uc[j2]) + wv[3] * bf2f(ud[j2]));
}

// ---------------------------------------------------------------------------
extern "C" void kernel_launch(void* const* d_in, const int* in_sizes, int n_in,
                              void* d_out, int out_size, void* d_ws, size_t ws_size,
                              hipStream_t stream) {
    (void)in_sizes; (void)n_in; (void)out_size; (void)ws_size;
    const float* x  = (const float*)d_in[0];
    const float* Wk = (const float*)d_in[1];
    const float* Wq = (const float*)d_in[2];
    const float* Wv = (const float*)d_in[3];
    float* out = (float*)d_out;

    unsigned short* Wt  = (unsigned short*)d_ws;       // 393216 shorts
    unsigned short* qkv = Wt + 393216;                 // k | q | (v slot unused)
    unsigned short* vT  = qkv + 6291456;               // 2097152
    unsigned short* po0 = vT + 2097152;
    unsigned short* po1 = po0 + 2097152;
    unsigned short* po3 = po1 + 2097152;
    unsigned short* po2 = qkv + 4194304;               // aliases unused v slot
    float* pm = (float*)d_ws;                          // 4 x 16384 (alias Wt)
    float* pl = pm + 65536;

    wtrans_kernel<<<1536, 256, 0, stream>>>(Wk, Wq, Wv, Wt);
    qkv_gemm2<<<512, 256, 0, stream>>>(x, Wt, qkv, vT);
    flash8_kernel<<<512, 512, 0, stream>>>(qkv, vT, po0, po1, po2, po3, pm, pl);
    combine4_kernel<<<1024, 256, 0, stream>>>(po0, po1, po2, po3, pm, pl, out);
}

// Round 11
// 78.910 us; speedup vs baseline: 1.4188x; 1.0180x over previous
//
#include <hip/hip_runtime.h>
#include <hip/hip_bf16.h>
#include <math.h>

// Problem constants
#define B_ 4
#define T_ 4096
#define C_ 1024
#define H_ 128
#define SCALE 0.08838834764831845f  // 1/sqrt(128)

typedef __attribute__((ext_vector_type(8))) short bf16x8;
typedef __attribute__((ext_vector_type(4))) float f32x4;

__device__ __forceinline__ unsigned short f2bf(float f) {
    union { float f; unsigned u; } x; x.f = f;
    unsigned r = x.u + 0x7FFF + ((x.u >> 16) & 1);
    return (unsigned short)(r >> 16);
}
__device__ __forceinline__ float bf2f(unsigned short u) {
    union { unsigned u; float f; } x; x.u = ((unsigned)u) << 16;
    return x.f;
}
__device__ __forceinline__ unsigned cvt_pk_bf16(float a, float b) {
    unsigned r;
    asm("v_cvt_pk_bf16_f32 %0, %1, %2" : "=v"(r) : "v"(a), "v"(b));
    return r;
}
// 16 floats -> 8 packed bf16 words via v_cvt_pk_bf16_f32 (lo = first arg)
__device__ __forceinline__ void cvt16(const float4& a, const float4& b,
                                      const float4& c, const float4& d,
                                      unsigned* t) {
    t[0]=cvt_pk_bf16(a.x,a.y); t[1]=cvt_pk_bf16(a.z,a.w);
    t[2]=cvt_pk_bf16(b.x,b.y); t[3]=cvt_pk_bf16(b.z,b.w);
    t[4]=cvt_pk_bf16(c.x,c.y); t[5]=cvt_pk_bf16(c.z,c.w);
    t[6]=cvt_pk_bf16(d.x,d.y); t[7]=cvt_pk_bf16(d.z,d.w);
}

// async global->LDS, 16B per lane. gsrc: per-lane global addr; ldst: wave-uniform base.
#define GLOAD16(gsrc, ldst)                                                        \
    __builtin_amdgcn_global_load_lds(                                              \
        (const __attribute__((address_space(1))) unsigned int*)(gsrc),             \
        (__attribute__((address_space(3))) unsigned int*)(ldst), 16, 0, 0)

// ---------------------------------------------------------------------------
// Kernel 1: W [C,H] fp32  ->  Wt [t][h][c] bf16  (transposed, cast)
// ---------------------------------------------------------------------------
__global__ __launch_bounds__(256) void wtrans_kernel(
        const float* __restrict__ Wk, const float* __restrict__ Wq,
        const float* __restrict__ Wv, unsigned short* __restrict__ Wt) {
    int tid = blockIdx.x * 256 + threadIdx.x;
    int t = tid >> 17;
    int r = tid & 131071;
    int c = r >> 7;
    int h = r & 127;
    const float* W = (t == 0) ? Wk : (t == 1) ? Wq : Wv;
    Wt[t * 131072 + h * 1024 + c] = f2bf(W[r]);
}

// ---------------------------------------------------------------------------
// Kernel 2: QKV GEMM v2. Grid 512 (2 blocks/CU): block = 64 M-rows x 192 N.
// Double-buffered; Bs via global_load_lds (swizzled); As reg-convert (cvt_pk)
// with issue-early/write-late; counted vmcnt(10). v-part written to vT.
// ---------------------------------------------------------------------------
__global__ __launch_bounds__(256, 2) void qkv_gemm2(
        const float* __restrict__ x, const unsigned short* __restrict__ Wt,
        unsigned short* __restrict__ qkv, unsigned short* __restrict__ vT) {
    __shared__ unsigned short As[2][64][72];      // 18 KB, padded (2-way free)
    __shared__ unsigned short Bs[2][192][64];     // 48 KB, unpadded+swizzled

    const int nsw = blockIdx.x;
    const int sw = (nsw & 7) * 64 + (nsw >> 3);   // XCD-contiguous m-bands
    const int m0 = (sw >> 1) * 64;
    const int nh = sw & 1;

    const int tid = threadIdx.x;
    const int lane = tid & 63;
    const int w = tid >> 6;
    const int fr = lane & 15;
    const int fq = lane >> 4;

    const int xrow = tid >> 2, xco = (tid & 3) * 16;
    const float* xsrc = x + (long)(m0 + xrow) * C_ + xco;
    const int brl = lane >> 3;
    const int bcolb = (((lane & 7) ^ brl) << 4);
    unsigned short* const bs_flat = &Bs[0][0][0];
    const unsigned short* wbase = Wt + (long)(nh * 192) * 1024;

    f32x4 acc[3][4];
#pragma unroll
    for (int i = 0; i < 3; i++)
#pragma unroll
        for (int rf = 0; rf < 4; rf++) acc[i][rf] = f32x4{0.f, 0.f, 0.f, 0.f};

    float4 xr0, xr1, xr2, xr3;
    xr0 = ((const float4*)xsrc)[0]; xr1 = ((const float4*)xsrc)[1];
    xr2 = ((const float4*)xsrc)[2]; xr3 = ((const float4*)xsrc)[3];
#pragma unroll
    for (int i = 0; i < 6; i++)
        GLOAD16(wbase + (long)(48*w + 8*i + brl) * 1024 + (bcolb >> 1),
                bs_flat + (w*6 + i) * 512);
    {
        unsigned tw[8];
        cvt16(xr0, xr1, xr2, xr3, tw);
        *(uint4*)&As[0][xrow][xco]     = uint4{tw[0], tw[1], tw[2], tw[3]};
        *(uint4*)&As[0][xrow][xco + 8] = uint4{tw[4], tw[5], tw[6], tw[7]};
    }

    int cur = 0;
    for (int k = 0; k < 16; ++k) {
        __syncthreads();   // X: all waves done MFMA(k-1); As[cur] writes visible
        const bool more = (k + 1) < 16;
        if (more) {
            const float* xs = xsrc + (k + 1) * 64;
            xr0 = ((const float4*)xs)[0]; xr1 = ((const float4*)xs)[1];
            xr2 = ((const float4*)xs)[2]; xr3 = ((const float4*)xs)[3];
            const int boff = (cur ^ 1) * 12288;    // shorts
#pragma unroll
            for (int i = 0; i < 6; i++)
                GLOAD16(wbase + (long)(48*w + 8*i + brl) * 1024 + (k + 1) * 64 + (bcolb >> 1),
                        bs_flat + boff + (w*6 + i) * 512);
            asm volatile("s_waitcnt vmcnt(10)" ::: "memory");  // Bs(k) landed
        } else {
            asm volatile("s_waitcnt vmcnt(0)" ::: "memory");
        }
        __syncthreads();   // Y: Bs[cur] visible from all waves

        const char* bsb = (const char*)bs_flat + cur * 24576;
        __builtin_amdgcn_s_setprio(1);
#pragma unroll
        for (int kk = 0; kk < 2; kk++) {
            bf16x8 a[4], bb[3];
#pragma unroll
            for (int rf = 0; rf < 4; rf++)
                a[rf] = *(const bf16x8*)&As[cur][rf*16 + fr][kk*32 + fq*8];
#pragma unroll
            for (int i = 0; i < 3; i++) {
                int row = (w*3 + i) * 16 + fr;
                bb[i] = *(const bf16x8*)(bsb + row*128 + ((((kk<<2) + fq) ^ (fr & 7)) << 4));
            }
#pragma unroll
            for (int i = 0; i < 3; i++)
#pragma unroll
                for (int rf = 0; rf < 4; rf++)
                    acc[i][rf] = __builtin_amdgcn_mfma_f32_16x16x32_bf16(
                        a[rf], bb[i], acc[i][rf], 0, 0, 0);
        }
        __builtin_amdgcn_s_setprio(0);

        if (more) {
            unsigned tw[8];
            cvt16(xr0, xr1, xr2, xr3, tw);
            *(uint4*)&As[cur ^ 1][xrow][xco]     = uint4{tw[0], tw[1], tw[2], tw[3]};
            *(uint4*)&As[cur ^ 1][xrow][xco + 8] = uint4{tw[4], tw[5], tw[6], tw[7]};
        }
        cur ^= 1;
    }

    // epilogue: k/q -> qkv (bf16 scalar), v -> vT directly (8B stores)
#pragma unroll
    for (int i = 0; i < 3; i++) {
        int nfg = nh*12 + w*3 + i;
        int t = nfg >> 3;
        int col = (nfg & 7) * 16 + fr;
        if (t < 2) {
#pragma unroll
            for (int rf = 0; rf < 4; rf++)
#pragma unroll
                for (int r = 0; r < 4; r++) {
                    int row = m0 + rf*16 + fq*4 + r;
                    qkv[(long)t * 2097152 + (long)row * 128 + col] = f2bf(acc[i][rf][r]);
                }
        } else {
            const int bb_ = m0 >> 12;
            const int trow = m0 & 4095;
#pragma unroll
            for (int rf = 0; rf < 4; rf++) {
                uint2 uu;
                uu.x = cvt_pk_bf16(acc[i][rf][0], acc[i][rf][1]);
                uu.y = cvt_pk_bf16(acc[i][rf][2], acc[i][rf][3]);
                *(uint2*)(vT + ((long)(bb_*128 + col)) * 4096 + trow + rf*16 + fq*4) = uu;
            }
        }
    }
}

// ---------------------------------------------------------------------------
// Kernel 3: flash9 = flash8 (1-barrier pipeline) + two softmax shortcuts:
//  (1) l computed by PV MFMA with an all-ones A-fragment (9th accumulator,
//      rescaled with the same alpha) -> no per-tile sum reduction;
//  (2) skip-path threshold check uses per-lane partial max only:
//      __all(pmax - m_r <= 8) == "all row maxes grew <= 8". Cross-lane max
//      reduce (2 shfl_xor) runs only on the rare rescale path.
// QB=128, KB=64, split-4, grid 512 = exactly 2 blocks/CU.
// ---------------------------------------------------------------------------
__global__ __launch_bounds__(512, 4) void flash9_kernel(
        const unsigned short* __restrict__ qkv,
        const unsigned short* __restrict__ vT,
        unsigned short* __restrict__ po0, unsigned short* __restrict__ po1,
        unsigned short* __restrict__ po2, unsigned short* __restrict__ po3,
        float* __restrict__ pm, float* __restrict__ pl) {
    __shared__ unsigned short k_lds[2][64][128];
    __shared__ unsigned short v_lds[2][128][64];

    const int n = blockIdx.x;
    const int half = n >> 8;
    const int m = n & 255;
    const int b = (m & 7) >> 1;
    const int r = ((m >> 3) << 1) | (m & 1);
    const int jj = r & 31;
    const int pq = r >> 5;
    const int qt = half ? (31 - jj) : jj;
    const int p = half * 2 + pq;
    const int q0 = qt * 128;
    const int ntt = (qt + 1) * 2;
    const int t0 = (p * ntt) >> 2;
    const int t1 = ((p + 1) * ntt) >> 2;

    const int tid = threadIdx.x;
    const int w = tid >> 6;
    const int lane = tid & 63;
    const int fr = lane & 15;
    const int fq = lane >> 4;

    const unsigned short* kbase = qkv + (long)b * T_ * H_;
    const unsigned short* vbase = vT + (long)b * H_ * T_;

    const int kcolb0 = ((lane & 15) << 4) ^ ((((lane >> 4)) & 7) << 4);
    const int kcolb1 = ((lane & 15) << 4) ^ (((4 + (lane >> 4)) & 7) << 4);
    const int krl = lane >> 4;
    const int vrl = lane >> 3;
    const int vcolb = ((lane & 7) << 4) ^ (vrl << 4);
    unsigned short* const klds_flat = &k_lds[0][0][0];
    unsigned short* const vlds_flat = &v_lds[0][0][0];
    const int scol = ((fq ^ (fr & 7)) << 4);

    bf16x8 qf[4];
    {
        const unsigned short* qptr = qkv + 2097152 + ((long)b*T_ + q0 + w*16 + fr) * H_;
#pragma unroll
        for (int ks = 0; ks < 4; ks++)
            qf[ks] = *(const bf16x8*)(qptr + ks*32 + fq*8);
    }

    bf16x8 ones;
    {
        union { unsigned short s[8]; bf16x8 v; } oc;
#pragma unroll
        for (int i = 0; i < 8; i++) oc.s[i] = 0x3F80;   // bf16 1.0
        ones = oc.v;
    }

    f32x4 acc[8];
#pragma unroll
    for (int i = 0; i < 8; i++) acc[i] = f32x4{0.f, 0.f, 0.f, 0.f};
    f32x4 acc_l = f32x4{0.f, 0.f, 0.f, 0.f};
    float m_r = -INFINITY;
    const int qrow = q0 + w*16 + fr;

    int cur = 0;
    if (t0 < t1) {
        const int kv0 = t0 * 64;
#pragma unroll
        for (int i = 0; i < 2; i++) {
            int kcolb = i ? kcolb1 : kcolb0;
            GLOAD16(kbase + (long)(kv0 + 8*w + 4*i + krl) * 128 + (kcolb >> 1),
                    klds_flat + w*1024 + i*512);
            GLOAD16(vbase + (long)(16*w + 8*i + vrl) * 4096 + kv0 + (vcolb >> 1),
                    vlds_flat + w*1024 + i*512);
        }
    }

    for (int t = t0; t < t1; ++t) {
        const int kv0 = t * 64;
        asm volatile("s_waitcnt vmcnt(0)" ::: "memory");  // own tile-t loads landed
        __syncthreads();  // all t-loads visible; all waves done reading buf^1
        if (t + 1 < t1) {
            const int kv0n = kv0 + 64;
            const int boff = (cur ^ 1) * 8192;
#pragma unroll
            for (int i = 0; i < 2; i++) {
                int kcolb = i ? kcolb1 : kcolb0;
                GLOAD16(kbase + (long)(kv0n + 8*w + 4*i + krl) * 128 + (kcolb >> 1),
                        klds_flat + boff + w*1024 + i*512);
                GLOAD16(vbase + (long)(16*w + 8*i + vrl) * 4096 + kv0n + (vcolb >> 1),
                        vlds_flat + boff + w*1024 + i*512);
            }
        }

        const char* kl = (const char*)k_lds + cur*16384 + fr*256;
        const char* vl = (const char*)v_lds + cur*16384 + fr*128;

        f32x4 s[4];
#pragma unroll
        for (int sf = 0; sf < 4; sf++) s[sf] = f32x4{0.f,0.f,0.f,0.f};
        __builtin_amdgcn_s_setprio(1);
#pragma unroll
        for (int sf = 0; sf < 4; sf++)
#pragma unroll
            for (int ks = 0; ks < 4; ks++) {
                bf16x8 kf = *(const bf16x8*)(kl + sf*4096 + (scol ^ (ks << 6)));
                s[sf] = __builtin_amdgcn_mfma_f32_16x16x32_bf16(kf, qf[ks], s[sf], 0, 0, 0);
            }
        __builtin_amdgcn_s_setprio(0);

        // scale + causal mask + per-lane partial max
        float pmax = -INFINITY;
        if (kv0 + 63 > q0 + 16*w) {
#pragma unroll
            for (int sf = 0; sf < 4; sf++)
#pragma unroll
                for (int rr = 0; rr < 4; rr++) {
                    int kv = kv0 + sf*16 + fq*4 + rr;
                    float sv = s[sf][rr] * SCALE;
                    sv = (kv > qrow) ? -INFINITY : sv;
                    s[sf][rr] = sv;
                    pmax = fmaxf(pmax, sv);
                }
        } else {
#pragma unroll
            for (int sf = 0; sf < 4; sf++)
#pragma unroll
                for (int rr = 0; rr < 4; rr++) {
                    float sv = s[sf][rr] * SCALE;
                    s[sf][rr] = sv;
                    pmax = fmaxf(pmax, sv);
                }
        }

        // defer-max: per-lane check suffices for "all rows grew <= 8"
        const bool skip = __all((m_r > -1e37f) & (pmax - m_r <= 8.f));
        float msub;
        if (skip) {
            msub = m_r;
        } else {
            float mx = fmaxf(pmax, __shfl_xor(pmax, 16, 64));
            mx = fmaxf(mx, __shfl_xor(mx, 32, 64));
            float mn = fmaxf(m_r, mx);
            msub = (mn == -INFINITY) ? 0.f : mn;
            float alpha = __expf(m_r - msub);
            m_r = mn;
#pragma unroll
            for (int hf = 0; hf < 8; hf++)
#pragma unroll
                for (int rr = 0; rr < 4; rr++) acc[hf][rr] *= alpha;
#pragma unroll
            for (int rr = 0; rr < 4; rr++) acc_l[rr] *= alpha;
        }

        float pv[4][4];
#pragma unroll
        for (int sf = 0; sf < 4; sf++)
#pragma unroll
            for (int rr = 0; rr < 4; rr++)
                pv[sf][rr] = __expf(s[sf][rr] - msub);

        unsigned pw[8];
#pragma unroll
        for (int sf = 0; sf < 4; sf++) {
            pw[2*sf]   = cvt_pk_bf16(pv[sf][0], pv[sf][1]);
            pw[2*sf+1] = cvt_pk_bf16(pv[sf][2], pv[sf][3]);
        }
        unsigned pbu[2][4];
        pbu[0][0]=0;pbu[0][1]=0;pbu[0][2]=0;pbu[0][3]=0;
        pbu[1][0]=0;pbu[1][1]=0;pbu[1][2]=0;pbu[1][3]=0;
        const int L1 = fr + 16 * ((fq & 1) * 2);
        const int L2 = L1 + 16;
        const int sel = (fq >> 1) & 1;
#pragma unroll
        for (int sf = 0; sf < 4; sf++) {
            unsigned w0 = (unsigned)__shfl((int)pw[2*sf],   L1, 64);
            unsigned w1 = (unsigned)__shfl((int)pw[2*sf+1], L1, 64);
            unsigned w2 = (unsigned)__shfl((int)pw[2*sf],   L2, 64);
            unsigned w3 = (unsigned)__shfl((int)pw[2*sf+1], L2, 64);
            if ((sf & 1) == sel) {
                int k2 = sf >> 1;
                pbu[k2][0] = w0; pbu[k2][1] = w1; pbu[k2][2] = w2; pbu[k2][3] = w3;
            }
        }
        union { unsigned u[4]; bf16x8 v; } pb0c, pb1c;
#pragma unroll
        for (int i = 0; i < 4; i++) { pb0c.u[i] = pbu[0][i]; pb1c.u[i] = pbu[1][i]; }
        bf16x8 pb0 = pb0c.v, pb1 = pb1c.v;

        __builtin_amdgcn_s_setprio(1);
#pragma unroll
        for (int hf = 0; hf < 8; hf++) {
            bf16x8 vf0 = *(const bf16x8*)(vl + hf*2048 + scol);
            bf16x8 vf1 = *(const bf16x8*)(vl + hf*2048 + (scol ^ 64));
            acc[hf] = __builtin_amdgcn_mfma_f32_16x16x32_bf16(vf0, pb0, acc[hf], 0, 0, 0);
            acc[hf] = __builtin_amdgcn_mfma_f32_16x16x32_bf16(vf1, pb1, acc[hf], 0, 0, 0);
        }
        // l-row: ones A-fragment -> every lane gets l for its q=fr in all slots
        acc_l = __builtin_amdgcn_mfma_f32_16x16x32_bf16(ones, pb0, acc_l, 0, 0, 0);
        acc_l = __builtin_amdgcn_mfma_f32_16x16x32_bf16(ones, pb1, acc_l, 0, 0, 0);
        __builtin_amdgcn_s_setprio(0);
        cur ^= 1;
    }

    unsigned short* po = (p == 0) ? po0 : (p == 1) ? po1 : (p == 2) ? po2 : po3;
    const float l_r = acc_l[0];
    float linv = (l_r > 0.f) ? (1.0f / l_r) : 0.f;
    const long obase = ((long)b * T_ + qrow) * H_;
#pragma unroll
    for (int hf = 0; hf < 8; hf++) {
        uint2 uu;
        uu.x = cvt_pk_bf16(acc[hf][0] * linv, acc[hf][1] * linv);
        uu.y = cvt_pk_bf16(acc[hf][2] * linv, acc[hf][3] * linv);
        *(uint2*)(po + obase + hf*16 + fq*4) = uu;
    }
    if (fq == 0) {
        pm[p * 16384 + b * T_ + qrow] = m_r;
        pl[p * 16384 + b * T_ + qrow] = l_r;
    }
}

// ---------------------------------------------------------------------------
// Kernel 4: combine the four KV-parts
// ---------------------------------------------------------------------------
__global__ __launch_bounds__(256) void combine4_kernel(
        const unsigned short* __restrict__ po0,
        const unsigned short* __restrict__ po1,
        const unsigned short* __restrict__ po2,
        const unsigned short* __restrict__ po3,
        const float* __restrict__ pm, const float* __restrict__ pl,
        float* __restrict__ out) {
    int idx = blockIdx.x * 256 + threadIdx.x;
    int row = idx >> 4;
    int seg = idx & 15;
    float mv[4], lv[4];
#pragma unroll
    for (int i = 0; i < 4; i++) { mv[i] = pm[i*16384 + row]; lv[i] = pl[i*16384 + row]; }
    float m = fmaxf(fmaxf(mv[0], mv[1]), fmaxf(mv[2], mv[3]));
    float wv[4]; float tot = 0.f;
#pragma unroll
    for (int i = 0; i < 4; i++) {
        wv[i] = (lv[i] > 0.f) ? __expf(mv[i] - m) * lv[i] : 0.f;
        tot += wv[i];
    }
    float inv = 1.0f / tot;
    long off = (long)row * H_ + seg * 8;
    unsigned short ua[8], ub[8], uc[8], ud[8];
    *(uint4*)ua = *(const uint4*)(po0 + off);
    *(uint4*)ub = *(const uint4*)(po1 + off);
    *(uint4*)uc = *(const uint4*)(po2 + off);
    *(uint4*)ud = *(const uint4*)(po3 + off);
    float* o = out + off;
#pragma unroll
    for (int j2 = 0; j2 < 8; j2++)
        o[j2] = inv * (wv[0] * bf2f(ua[j2]) + wv[1] * bf2f(ub[j2]) +
                       wv[2] * bf2f(uc[j2]) + wv[3] * bf2f(ud[j2]));
}

// ---------------------------------------------------------------------------
extern "C" void kernel_launch(void* const* d_in, const int* in_sizes, int n_in,
                              void* d_out, int out_size, void* d_ws, size_t ws_size,
                              hipStream_t stream) {
    (void)in_sizes; (void)n_in; (void)out_size; (void)ws_size;
    const float* x  = (const float*)d_in[0];
    const float* Wk = (const float*)d_in[1];
    const float* Wq = (const float*)d_in[2];
    const float* Wv = (const float*)d_in[3];
    float* out = (float*)d_out;

    unsigned short* Wt  = (unsigned short*)d_ws;       // 393216 shorts
    unsigned short* qkv = Wt + 393216;                 // k | q | (v slot unused)
    unsigned short* vT  = qkv + 6291456;               // 2097152
    unsigned short* po0 = vT + 2097152;
    unsigned short* po1 = po0 + 2097152;
    unsigned short* po3 = po1 + 2097152;
    unsigned short* po2 = qkv + 4194304;               // aliases unused v slot
    float* pm = (float*)d_ws;                          // 4 x 16384 (alias Wt)
    float* pl = pm + 65536;

    wtrans_kernel<<<1536, 256, 0, stream>>>(Wk, Wq, Wv, Wt);
    qkv_gemm2<<<512, 256, 0, stream>>>(x, Wt, qkv, vT);
    flash9_kernel<<<512, 512, 0, stream>>>(qkv, vT, po0, po1, po2, po3, pm, pl);
    combine4_kernel<<<1024, 256, 0, stream>>>(po0, po1, po2, po3, pm, pl, out);
}